// Round 16
// baseline (3912.122 us; speedup 1.0000x reference)
//
#include <hip/hip_runtime.h>
#include <stdint.h>

#define B_ 2
#define S_ 2048
#define D_ 4096
#define H_ 32
#define KV_ 8
#define HD_ 128
#define M_ (B_*S_)          // 4096 rows (b*S+s)
#define NQ_ (H_*HD_)        // 4096
#define NKV_ (KV_*HD_)      // 1024

typedef unsigned short u16;
typedef __bf16 bf16x8 __attribute__((ext_vector_type(8)));
typedef float f32x4 __attribute__((ext_vector_type(4)));
typedef u16 u16x8 __attribute__((ext_vector_type(8)));
typedef u16 u16x4 __attribute__((ext_vector_type(4)));

__device__ __forceinline__ u16 f2bf(float f) {
  union { float f; unsigned u; } v; v.f = f;
  unsigned r = v.u + 0x7fffu + ((v.u >> 16) & 1u);
  return (u16)(r >> 16);
}
__device__ __forceinline__ u16 f2bft(float f) {  // truncating (for P; values in [0,4.2])
  union { float f; unsigned u; } v; v.f = f;
  return (u16)(v.u >> 16);
}
__device__ __forceinline__ float bf2f(u16 u) {
  union { unsigned u; float f; } v; v.u = ((unsigned)u) << 16;
  return v.f;
}
__device__ __forceinline__ f32x4 mfma16(bf16x8 a, bf16x8 b, f32x4 c) {
  return __builtin_amdgcn_mfma_f32_16x16x32_bf16(a, b, c, 0, 0, 0);
}

#define GLDS16(gp, lp) __builtin_amdgcn_global_load_lds( \
    (const __attribute__((address_space(1))) unsigned int*)(gp), \
    (__attribute__((address_space(3))) unsigned int*)(lp), 16, 0, 0)

// ---------------- fp32 -> bf16 convert (vectorized) ----------------
__global__ __launch_bounds__(256) void cvt_bf16(const float* __restrict__ in,
                                                u16* __restrict__ out, int n) {
  int i = (blockIdx.x * 256 + threadIdx.x) * 8;
  if (i >= n) return;
  float4 a = *(const float4*)(in + i);
  float4 b = *(const float4*)(in + i + 4);
  u16x8 o;
  o[0]=f2bf(a.x); o[1]=f2bf(a.y); o[2]=f2bf(a.z); o[3]=f2bf(a.w);
  o[4]=f2bf(b.x); o[5]=f2bf(b.y); o[6]=f2bf(b.z); o[7]=f2bf(b.w);
  *(u16x8*)(out + i) = o;
}

// -------- transpose + convert: out[c][r] = in[r][c], 64x64, vectorized --------
__global__ __launch_bounds__(256) void tcvt(const float* __restrict__ in,
                                            u16* __restrict__ out, int R, int C) {
  __shared__ float tf[64][65];
  int c0 = blockIdx.x * 64, r0 = blockIdx.y * 64;
  int l16 = threadIdx.x & 15, r16 = threadIdx.x >> 4;
  #pragma unroll
  for (int p = 0; p < 4; ++p) {
    int r = p * 16 + r16;
    float4 v = *(const float4*)(in + (size_t)(r0 + r) * C + c0 + l16 * 4);
    tf[r][l16 * 4 + 0] = v.x; tf[r][l16 * 4 + 1] = v.y;
    tf[r][l16 * 4 + 2] = v.z; tf[r][l16 * 4 + 3] = v.w;
  }
  __syncthreads();
  int oc = threadIdx.x >> 2, ch = threadIdx.x & 3;
  u16x8 o1, o2;
  #pragma unroll
  for (int i = 0; i < 8; ++i) o1[i] = f2bf(tf[ch * 16 + i][oc]);
  #pragma unroll
  for (int i = 0; i < 8; ++i) o2[i] = f2bf(tf[ch * 16 + 8 + i][oc]);
  *(u16x8*)(out + (size_t)(c0 + oc) * R + r0 + ch * 16) = o1;
  *(u16x8*)(out + (size_t)(c0 + oc) * R + r0 + ch * 16 + 8) = o2;
}

// ------- 256x256 GEMM, 3-buf rotation + reg pipeline + WAVE-PARITY ANTI-PHASE -------
// Pipe arithmetic (R15): per BK=32 tile per CU, MFMA = 1242 cyc and LDS-read =
// ~1150 cyc; lockstep waves serialize them (reads-then-MFMA for all 8 waves)
// -> 2616 cyc measured. Fix: waves 0-3 {reads; MFMA}, waves 4-7 {MFMA; reads}.
// Waves w and w+4 share a SIMD -> each SIMD overlaps one wave's LDS phase with
// the other's MFMA phase. No new barriers; buffers already disjoint
// (read (t+1)%3, stage (t+2)%3). DOROPE: fused RoPE epilogue (lane-pair shfl).
template<int OUTMODE, bool DOROPE>
__global__ __launch_bounds__(512, 2) void gemm256(const u16* __restrict__ A,
    const u16* __restrict__ BT, void* __restrict__ Cv,
    const float* __restrict__ FC, const float* __restrict__ FS,
    int M, int N, int K) {
  extern __shared__ __attribute__((aligned(16))) u16 DL[];  // 3 x 16384 u16
  const int tid = threadIdx.x;
  const int nbx = N >> 8;
  const int cpx = gridDim.x >> 3;                 // grid % 8 == 0
  const int swzb = (blockIdx.x & 7) * cpx + (blockIdx.x >> 3);
  const int bn0 = (swzb % nbx) << 8, bm0 = (swzb / nbx) << 8;
  const int l = tid & 63, g = l >> 4, q = l & 15;
  const int w = tid >> 6;
  const int wm = (w >> 2) * 128, wn = (w & 3) * 64;
  const bool rdFirst = (w < 4);                   // SIMD s hosts waves s, s+4
  const int nt = K >> 5;   // BK = 32
  f32x4 acc[8][4] = {};

  const int srow = tid >> 2, schunk = tid & 3;
  const int ssw = (schunk ^ ((srow >> 1) & 3)) << 3;
  const u16* gA0 = A  + (size_t)(bm0 + srow) * K + ssw;
  const u16* gA1 = gA0 + (size_t)128 * K;
  const u16* gB0 = BT + (size_t)(bn0 + srow) * K + ssw;
  const u16* gB1 = gB0 + (size_t)128 * K;

  auto STAGE = [&](int t) {
    const int kt = t << 5;
    u16* d = DL + (t % 3) * 16384;
    GLDS16(gA0 + kt, d + tid * 8);
    GLDS16(gA1 + kt, d + 4096 + tid * 8);
    GLDS16(gB0 + kt, d + 8192 + tid * 8);
    GLDS16(gB1 + kt, d + 12288 + tid * 8);
  };

  const u16* ra = DL + (wm + q) * 32 + ((g ^ (((wm + q) >> 1) & 3)) << 3);
  const u16* rb = DL + 8192 + (wn + q) * 32 + ((g ^ (((wn + q) >> 1) & 3)) << 3);

  bf16x8 aC[8], aN[8], bC[4], bN[4];

  STAGE(0); STAGE(1);
  asm volatile("s_waitcnt vmcnt(4)" ::: "memory");
  __builtin_amdgcn_s_barrier();
  #pragma unroll
  for (int m = 0; m < 8; ++m) aC[m] = *(const bf16x8*)(ra + m * 512);
  #pragma unroll
  for (int n = 0; n < 4; ++n) bC[n] = *(const bf16x8*)(rb + n * 512);

  auto TILE = [&](int t, bf16x8 (&ac)[8], bf16x8 (&bc)[4],
                         bf16x8 (&an)[8], bf16x8 (&bn)[4]) {
    if (t + 2 < nt) {
      STAGE(t + 2);
      asm volatile("s_waitcnt vmcnt(4)" ::: "memory");
    } else {
      asm volatile("s_waitcnt vmcnt(0)" ::: "memory");
    }
    __builtin_amdgcn_s_barrier();
    const bool hasNext = (t + 1 < nt);
    const u16* pa = ra + ((t + 1) % 3) * 16384;
    const u16* pb = rb + ((t + 1) % 3) * 16384;
    if (rdFirst) {
      if (hasNext) {
        #pragma unroll
        for (int m = 0; m < 8; ++m) an[m] = *(const bf16x8*)(pa + m * 512);
        #pragma unroll
        for (int n = 0; n < 4; ++n) bn[n] = *(const bf16x8*)(pb + n * 512);
      }
      __builtin_amdgcn_s_setprio(1);
      #pragma unroll
      for (int m = 0; m < 8; ++m) {
        acc[m][0] = mfma16(ac[m], bc[0], acc[m][0]);
        acc[m][1] = mfma16(ac[m], bc[1], acc[m][1]);
        acc[m][2] = mfma16(ac[m], bc[2], acc[m][2]);
        acc[m][3] = mfma16(ac[m], bc[3], acc[m][3]);
      }
      __builtin_amdgcn_s_setprio(0);
    } else {
      __builtin_amdgcn_s_setprio(1);
      #pragma unroll
      for (int m = 0; m < 8; ++m) {
        acc[m][0] = mfma16(ac[m], bc[0], acc[m][0]);
        acc[m][1] = mfma16(ac[m], bc[1], acc[m][1]);
        acc[m][2] = mfma16(ac[m], bc[2], acc[m][2]);
        acc[m][3] = mfma16(ac[m], bc[3], acc[m][3]);
      }
      __builtin_amdgcn_s_setprio(0);
      if (hasNext) {
        #pragma unroll
        for (int m = 0; m < 8; ++m) an[m] = *(const bf16x8*)(pa + m * 512);
        #pragma unroll
        for (int n = 0; n < 4; ++n) bn[n] = *(const bf16x8*)(pb + n * 512);
      }
    }
  };

  for (int t = 0; t < nt; t += 2) {
    TILE(t,     aC, bC, aN, bN);
    TILE(t + 1, aN, bN, aC, bC);
  }

  #pragma unroll
  for (int m = 0; m < 8; ++m)
    #pragma unroll
    for (int n = 0; n < 4; ++n) {
      const int col = bn0 + wn + n * 16 + q;
      if (DOROPE) {
        const int fi = (col & 127) >> 1;
        const float sgn = (q & 1) ? 1.0f : -1.0f;
        #pragma unroll
        for (int j = 0; j < 4; ++j) {
          int row = bm0 + wm + m * 16 + g * 4 + j;
          int pos = row & (S_ - 1);
          float c = FC[pos * 64 + fi], s = FS[pos * 64 + fi];
          float own = acc[m][n][j];
          float par = __shfl_xor(own, 1);
          ((u16*)Cv)[(size_t)row * N + col] = f2bf(own * c + par * s * sgn);
        }
      } else {
        #pragma unroll
        for (int j = 0; j < 4; ++j) {
          size_t off = (size_t)(bm0 + wm + m * 16 + g * 4 + j) * N + col;
          if (OUTMODE == 1) ((float*)Cv)[off] = acc[m][n][j];
          else              ((u16*)Cv)[off]  = f2bf(acc[m][n][j]);
        }
      }
    }
}

// ------- KV projection GEMM: BM=256 x BN=128, 3-buf reg pipeline + anti-phase -------
// K branch (col<1024): fused RoPE. V branch: tiled V^T layout.
__global__ __launch_bounds__(512, 2) void gemm_kv(const u16* __restrict__ A,
    const u16* __restrict__ BT, u16* __restrict__ Ck, u16* __restrict__ Cvt,
    const float* __restrict__ FC, const float* __restrict__ FS,
    int M, int N, int K) {
  extern __shared__ __attribute__((aligned(16))) u16 DL[];  // 3 x 12288 u16
  const int tid = threadIdx.x;
  const int nbx = N >> 7;                          // 16
  const int cpx = gridDim.x >> 3;
  const int swzb = (blockIdx.x & 7) * cpx + (blockIdx.x >> 3);
  const int bn0 = (swzb % nbx) << 7, bm0 = (swzb / nbx) << 8;
  const int l = tid & 63, g = l >> 4, q = l & 15;
  const int w = tid >> 6;
  const int wm = (w >> 2) * 128, wn = (w & 3) * 32;
  const bool rdFirst = (w < 4);
  const int nt = K >> 5;
  f32x4 acc[8][2] = {};

  const int srow = tid >> 2, schunk = tid & 3;
  const int ssw = (schunk ^ ((srow >> 1) & 3)) << 3;
  const u16* gA0 = A  + (size_t)(bm0 + srow) * K + ssw;
  const u16* gA1 = gA0 + (size_t)128 * K;
  const u16* gB0 = BT + (size_t)(bn0 + srow) * K + ssw;

  auto STAGE = [&](int t) {
    const int kt = t << 5;
    u16* d = DL + (t % 3) * 12288;
    GLDS16(gA0 + kt, d + tid * 8);
    GLDS16(gA1 + kt, d + 4096 + tid * 8);
    GLDS16(gB0 + kt, d + 8192 + tid * 8);
  };

  const u16* ra = DL + (wm + q) * 32 + ((g ^ (((wm + q) >> 1) & 3)) << 3);
  const u16* rb = DL + 8192 + (wn + q) * 32 + ((g ^ (((wn + q) >> 1) & 3)) << 3);

  bf16x8 aC[8], aN[8], bC[2], bN[2];

  STAGE(0); STAGE(1);
  asm volatile("s_waitcnt vmcnt(3)" ::: "memory");
  __builtin_amdgcn_s_barrier();
  #pragma unroll
  for (int m = 0; m < 8; ++m) aC[m] = *(const bf16x8*)(ra + m * 512);
  #pragma unroll
  for (int n = 0; n < 2; ++n) bC[n] = *(const bf16x8*)(rb + n * 512);

  auto TILE = [&](int t, bf16x8 (&ac)[8], bf16x8 (&bc)[2],
                         bf16x8 (&an)[8], bf16x8 (&bn)[2]) {
    if (t + 2 < nt) {
      STAGE(t + 2);
      asm volatile("s_waitcnt vmcnt(3)" ::: "memory");
    } else {
      asm volatile("s_waitcnt vmcnt(0)" ::: "memory");
    }
    __builtin_amdgcn_s_barrier();
    const bool hasNext = (t + 1 < nt);
    const u16* pa = ra + ((t + 1) % 3) * 12288;
    const u16* pb = rb + ((t + 1) % 3) * 12288;
    if (rdFirst) {
      if (hasNext) {
        #pragma unroll
        for (int m = 0; m < 8; ++m) an[m] = *(const bf16x8*)(pa + m * 512);
        #pragma unroll
        for (int n = 0; n < 2; ++n) bn[n] = *(const bf16x8*)(pb + n * 512);
      }
      __builtin_amdgcn_s_setprio(1);
      #pragma unroll
      for (int m = 0; m < 8; ++m) {
        acc[m][0] = mfma16(ac[m], bc[0], acc[m][0]);
        acc[m][1] = mfma16(ac[m], bc[1], acc[m][1]);
      }
      __builtin_amdgcn_s_setprio(0);
    } else {
      __builtin_amdgcn_s_setprio(1);
      #pragma unroll
      for (int m = 0; m < 8; ++m) {
        acc[m][0] = mfma16(ac[m], bc[0], acc[m][0]);
        acc[m][1] = mfma16(ac[m], bc[1], acc[m][1]);
      }
      __builtin_amdgcn_s_setprio(0);
      if (hasNext) {
        #pragma unroll
        for (int m = 0; m < 8; ++m) an[m] = *(const bf16x8*)(pa + m * 512);
        #pragma unroll
        for (int n = 0; n < 2; ++n) bn[n] = *(const bf16x8*)(pb + n * 512);
      }
    }
  };

  for (int t = 0; t < nt; t += 2) {
    TILE(t,     aC, bC, aN, bN);
    TILE(t + 1, aN, bN, aC, bC);
  }

  #pragma unroll
  for (int m = 0; m < 8; ++m)
    #pragma unroll
    for (int n = 0; n < 2; ++n) {
      int row0 = bm0 + wm + m * 16 + g * 4;
      int col  = bn0 + wn + n * 16 + q;
      if (col < 1024) {       // K head-cols: apply RoPE (uniform per 16-lane blk)
        const int fi = (col & 127) >> 1;
        const float sgn = (q & 1) ? 1.0f : -1.0f;
        #pragma unroll
        for (int j = 0; j < 4; ++j) {
          int row = row0 + j;
          int pos = row & (S_ - 1);
          float c = FC[pos * 64 + fi], s = FS[pos * 64 + fi];
          float own = acc[m][n][j];
          float par = __shfl_xor(own, 1);
          Ck[(size_t)row * 1024 + col] = f2bf(own * c + par * s * sgn);
        }
      } else {
        int c2 = col - 1024;
        u16x4 pk;
        #pragma unroll
        for (int j = 0; j < 4; ++j) pk[j] = f2bf(acc[m][n][j]);
        size_t off = ((size_t)((row0 >> 11) * KV_ + (c2 >> 7)) * 32 + ((row0 >> 6) & 31)) * 8192
                   + (size_t)(c2 & 127) * 64 + (row0 & 63);
        *(u16x4*)(Cvt + off) = pk;
      }
    }
}

// ---------------- causal GQA flash attention (swapped-QK^T) ----------------
// R11 version (138us measured). grid (16,H,B)=1024 blocks=4/CU; 4 waves;
// QT=64 (16 q-rows/wave), pairing {31-p, p} -> uniform 33 KT=64 iters/block.
// Lessons: launch_bounds arg2 caps VGPR at 512/N (R12: (256,8)=32 VGPR=spill);
// grid=capacity kills backfill (R13). Pairing at 4 blocks/CU is the optimum.
__global__ __launch_bounds__(256, 4) void attn_kernel(
    const u16* __restrict__ Qb, const u16* __restrict__ Kb,
    const u16* __restrict__ VTg, u16* __restrict__ Ob) {
  __shared__ __attribute__((aligned(16))) u16 SM[20480]; // 40KB
  u16* Ks = SM;            // [64][128] swz(row&7)
  u16* Vs = SM + 8192;     // [128][64] swz(row&7)
  u16* Ps = SM + 16384;    // 4 waves x [16 q][64 k], 16B-chunk ^ (q&7)
  const int pr = blockIdx.x;            // 0..15
  const int h = blockIdx.y, b = blockIdx.z;
  const int kvh = h >> 2;               // N_REP = 4
  const int tid = threadIdx.x, w = tid >> 6, l = tid & 63, g = l >> 4, ql = l & 15;
  const float SL2E = 0.08838834764831845f * 1.4426950408889634f;
  const u16* Qh = Qb + (size_t)b * S_ * NQ_ + h * HD_;
  const u16* Kh = Kb + ((size_t)b * S_ * KV_ + kvh) * HD_;
  const u16* Vh = VTg + (size_t)(b * KV_ + kvh) * (32 * 8192);
  u16* Oh = Ob + (size_t)b * S_ * NQ_ + h * HD_;

  for (int ph = 0; ph < 2; ++ph) {
    const int qt = ph ? pr : 31 - pr;
    __syncthreads();   // SM (epilogue scratch) free before restaging
    bf16x8 aq[4];
    #pragma unroll
    for (int kk = 0; kk < 4; ++kk)
      aq[kk] = *(const bf16x8*)(Qh + (size_t)(qt * 64 + w * 16 + ql) * NQ_ + kk * 32 + g * 8);

    f32x4 o[8] = {};
    float mrow = -3.0e38f, lrow = 0.f;

    const int nkt = qt + 1;
    for (int kt = 0; kt < nkt; ++kt) {
      #pragma unroll
      for (int p = 0; p < 4; ++p) {   // K: [64][128]
        int c = tid + p * 256;
        int row = c >> 4, slot = c & 15;
        GLDS16(Kh + (size_t)(kt * 64 + row) * (KV_ * HD_) + ((slot ^ (row & 7)) << 3), Ks + c * 8);
      }
      #pragma unroll
      for (int p = 0; p < 4; ++p) {   // V^T: [128][64] from contiguous 16KB tile
        int c = tid + p * 256;
        int row = c >> 3, slot = c & 7;
        GLDS16(Vh + (size_t)kt * 8192 + row * 64 + ((slot ^ (row & 7)) << 3), Vs + c * 8);
      }
      asm volatile("s_waitcnt vmcnt(0)" ::: "memory");
      __builtin_amdgcn_s_barrier();

      if (kt * 64 <= qt * 64 + w * 16 + 15) {   // wave-uniform activity gate
        // ---- S^T = K * Q^T ----
        f32x4 sc[4] = {};
        #pragma unroll
        for (int kk = 0; kk < 4; ++kk) {
          bf16x8 bk[4];
          #pragma unroll
          for (int n = 0; n < 4; ++n) {
            int row = n * 16 + ql;
            bk[n] = *(const bf16x8*)(Ks + row * 128 + (((kk * 4 + g) ^ (row & 7)) << 3));
          }
          #pragma unroll
          for (int n = 0; n < 4; ++n)
            sc[n] = mfma16(bk[n], aq[kk], sc[n]);
        }
        // ---- causal mask (diagonal tiles only); lane holds k=kt*64+n*16+g*4+j, q=ql ----
        const int qglob = qt * 64 + w * 16 + ql;
        if (kt * 64 + 63 > qt * 64 + w * 16) {
          #pragma unroll
          for (int n = 0; n < 4; ++n)
            #pragma unroll
            for (int j = 0; j < 4; ++j)
              if (kt * 64 + n * 16 + g * 4 + j > qglob) sc[n][j] = -3.0e38f;
        }
        // ---- online softmax: in-lane over 16 k-vals, then xor16/xor32 ----
        float mx = sc[0][0];
        #pragma unroll
        for (int n = 0; n < 4; ++n)
          #pragma unroll
          for (int j = 0; j < 4; ++j) mx = fmaxf(mx, sc[n][j]);
        mx = fmaxf(mx, __shfl_xor(mx, 16));
        mx = fmaxf(mx, __shfl_xor(mx, 32));
        if (!__all(mx - mrow <= 16.0f)) {      // defer-max: P bounded by 2^2.04
          float mnew = fmaxf(mrow, mx);
          float f = exp2f((mrow - mnew) * SL2E);
          lrow *= f;
          #pragma unroll
          for (int m = 0; m < 8; ++m) o[m] *= f;
          mrow = mnew;
        }
        float rs = 0.f;
        #pragma unroll
        for (int n = 0; n < 4; ++n)
          #pragma unroll
          for (int j = 0; j < 4; ++j) {
            float pv = exp2f((sc[n][j] - mrow) * SL2E);
            sc[n][j] = pv; rs += pv;
          }
        rs += __shfl_xor(rs, 16);
        rs += __shfl_xor(rs, 32);
        lrow += rs;
        // ---- P -> LDS: [16 q][64 k], 16B chunk ^ (q&7); 4 x u16x4 writes ----
        u16* Pw = Ps + w * 1024;
        #pragma unroll
        for (int n = 0; n < 4; ++n) {
          u16x4 pk;
          #pragma unroll
          for (int j = 0; j < 4; ++j) pk[j] = f2bft(sc[n][j]);
          *(u16x4*)(Pw + ql * 64 + (((n * 2 + (g >> 1)) ^ (ql & 7)) << 3) + (g & 1) * 4) = pk;
        }
        // ---- PV: O^T = V^T * P^T ----
        #pragma unroll
        for (int kk2 = 0; kk2 < 2; ++kk2) {
          bf16x8 bp = *(const bf16x8*)(Pw + ql * 64 + (((kk2 * 4 + g) ^ (ql & 7)) << 3));
          #pragma unroll
          for (int m = 0; m < 8; ++m) {
            int row = m * 16 + ql;
            bf16x8 av = *(const bf16x8*)(Vs + row * 64 + (((kk2 * 4 + g) ^ (row & 7)) << 3));
            o[m] = mfma16(av, bp, o[m]);
          }
        }
      }
      __builtin_amdgcn_s_barrier();   // all waves done with Ks/Vs before restage
    }
    // ---- epilogue: normalize (lane-local), transpose via LDS, store ----
    __syncthreads();
    u16* OS = SM; // [64][136]
    float linv = 1.0f / lrow;
    #pragma unroll
    for (int m = 0; m < 8; ++m)
      #pragma unroll
      for (int j = 0; j < 4; ++j)
        OS[(w * 16 + ql) * 136 + m * 16 + g * 4 + j] = f2bf(o[m][j] * linv);
    __syncthreads();
    #pragma unroll
    for (int p = 0; p < 4; ++p) {
      int c = tid + p * 256;
      int row = c >> 4, col8 = c & 15;
      u16x8 d = *(const u16x8*)(OS + row * 136 + col8 * 8);
      *(u16x8*)(Oh + (size_t)(qt * 64 + row) * NQ_ + col8 * 8) = d;
    }
  }
}

extern "C" void kernel_launch(void* const* d_in, const int* in_sizes, int n_in,
                              void* d_out, int out_size, void* d_ws, size_t ws_size,
                              hipStream_t stream) {
  const float* x  = (const float*)d_in[0];
  const float* fc = (const float*)d_in[1];
  const float* fs = (const float*)d_in[2];
  // d_in[3] = mask (causal, applied analytically)
  const float* wq = (const float*)d_in[4];
  const float* wk = (const float*)d_in[5];
  const float* wv = (const float*)d_in[6];
  const float* wo = (const float*)d_in[7];

  char* ws = (char*)d_ws;
  u16* xb  = (u16*)(ws + 0);          // 33554432 B
  u16* wqT = (u16*)(ws + 33554432);   // 33554432
  u16* wkT = (u16*)(ws + 67108864);   // 8388608   (wkT||wvT = [2048][4096])
  u16* wvT = (u16*)(ws + 75497472);   // 8388608
  u16* woT = (u16*)(ws + 83886080);   // 33554432
  u16* qb  = (u16*)(ws + 117440512);  // 33554432
  u16* kb  = (u16*)(ws + 150994944);  // 8388608
  u16* vtg = (u16*)(ws + 159383552);  // 8388608  (V^T tiled: [B][KV][32][128][64])
  u16* ob  = (u16*)(ws + 167772160);  // 33554432  -> total 201326592
  if (ws_size < 201326592u) return;

  cvt_bf16<<<(M_ * D_) / (8 * 256), 256, 0, stream>>>(x, xb, M_ * D_);
  tcvt<<<dim3(NQ_ / 64, D_ / 64), 256, 0, stream>>>(wq, wqT, D_, NQ_);
  tcvt<<<dim3(NKV_ / 64, D_ / 64), 256, 0, stream>>>(wk, wkT, D_, NKV_);
  tcvt<<<dim3(NKV_ / 64, D_ / 64), 256, 0, stream>>>(wv, wvT, D_, NKV_);
  tcvt<<<dim3(D_ / 64, NQ_ / 64), 256, 0, stream>>>(wo, woT, NQ_, D_);

  // Q projection + fused RoPE
  gemm256<0, true><<<(NQ_ / 256) * (M_ / 256), 512, 98304, stream>>>(
      xb, wqT, qb, fc, fs, M_, NQ_, D_);
  // fused K+V projection (K branch: fused RoPE; V: tiled V^T layout)
  gemm_kv<<<(2048 / 128) * (M_ / 256), 512, 73728, stream>>>(
      xb, wkT, kb, vtg, fc, fs, M_, 2048, D_);

  attn_kernel<<<dim3(16, H_, B_), 256, 0, stream>>>(qb, kb, vtg, ob);

  gemm256<1, false><<<(D_ / 256) * (M_ / 256), 512, 98304, stream>>>(
      ob, woT, d_out, fc, fs, M_, D_, NQ_);
}

// Round 17
// 513.088 us; speedup vs baseline: 7.6247x; 7.6247x over previous
//
#include <hip/hip_runtime.h>
#include <stdint.h>

#define B_ 2
#define S_ 2048
#define D_ 4096
#define H_ 32
#define KV_ 8
#define HD_ 128
#define M_ (B_*S_)          // 4096 rows (b*S+s)
#define NQ_ (H_*HD_)        // 4096
#define NKV_ (KV_*HD_)      // 1024

typedef unsigned short u16;
typedef __bf16 bf16x8 __attribute__((ext_vector_type(8)));
typedef float f32x4 __attribute__((ext_vector_type(4)));
typedef u16 u16x8 __attribute__((ext_vector_type(8)));
typedef u16 u16x4 __attribute__((ext_vector_type(4)));

__device__ __forceinline__ u16 f2bf(float f) {
  union { float f; unsigned u; } v; v.f = f;
  unsigned r = v.u + 0x7fffu + ((v.u >> 16) & 1u);
  return (u16)(r >> 16);
}
__device__ __forceinline__ u16 f2bft(float f) {  // truncating (for P; values in [0,4.2])
  union { float f; unsigned u; } v; v.f = f;
  return (u16)(v.u >> 16);
}
__device__ __forceinline__ float bf2f(u16 u) {
  union { unsigned u; float f; } v; v.u = ((unsigned)u) << 16;
  return v.f;
}
__device__ __forceinline__ f32x4 mfma16(bf16x8 a, bf16x8 b, f32x4 c) {
  return __builtin_amdgcn_mfma_f32_16x16x32_bf16(a, b, c, 0, 0, 0);
}

#define GLDS16(gp, lp) __builtin_amdgcn_global_load_lds( \
    (const __attribute__((address_space(1))) unsigned int*)(gp), \
    (__attribute__((address_space(3))) unsigned int*)(lp), 16, 0, 0)

// ---------------- fp32 -> bf16 convert (vectorized) ----------------
__global__ __launch_bounds__(256) void cvt_bf16(const float* __restrict__ in,
                                                u16* __restrict__ out, int n) {
  int i = (blockIdx.x * 256 + threadIdx.x) * 8;
  if (i >= n) return;
  float4 a = *(const float4*)(in + i);
  float4 b = *(const float4*)(in + i + 4);
  u16x8 o;
  o[0]=f2bf(a.x); o[1]=f2bf(a.y); o[2]=f2bf(a.z); o[3]=f2bf(a.w);
  o[4]=f2bf(b.x); o[5]=f2bf(b.y); o[6]=f2bf(b.z); o[7]=f2bf(b.w);
  *(u16x8*)(out + i) = o;
}

// -------- transpose + convert: out[c][r] = in[r][c], 64x64, vectorized --------
__global__ __launch_bounds__(256) void tcvt(const float* __restrict__ in,
                                            u16* __restrict__ out, int R, int C) {
  __shared__ float tf[64][65];
  int c0 = blockIdx.x * 64, r0 = blockIdx.y * 64;
  int l16 = threadIdx.x & 15, r16 = threadIdx.x >> 4;
  #pragma unroll
  for (int p = 0; p < 4; ++p) {
    int r = p * 16 + r16;
    float4 v = *(const float4*)(in + (size_t)(r0 + r) * C + c0 + l16 * 4);
    tf[r][l16 * 4 + 0] = v.x; tf[r][l16 * 4 + 1] = v.y;
    tf[r][l16 * 4 + 2] = v.z; tf[r][l16 * 4 + 3] = v.w;
  }
  __syncthreads();
  int oc = threadIdx.x >> 2, ch = threadIdx.x & 3;
  u16x8 o1, o2;
  #pragma unroll
  for (int i = 0; i < 8; ++i) o1[i] = f2bf(tf[ch * 16 + i][oc]);
  #pragma unroll
  for (int i = 0; i < 8; ++i) o2[i] = f2bf(tf[ch * 16 + 8 + i][oc]);
  *(u16x8*)(out + (size_t)(c0 + oc) * R + r0 + ch * 16) = o1;
  *(u16x8*)(out + (size_t)(c0 + oc) * R + r0 + ch * 16 + 8) = o2;
}

// ------- 256x256 GEMM, 3-buf rotation + FULL cross-tile register pipeline -------
// (R10/R15 structure, ~1015 TF.) R16 LESSON: wave-parity anti-phase (branchy
// TILE writing an/bn on two paths) demoted the bf16x8 arrays to scratch --
// WRITE_SIZE 32KB -> 6.1GB, 14x slower, with VGPR_Count unchanged. Keep the
// TILE body straight-line. DOROPE: fused RoPE epilogue (lane-pair shfl).
template<int OUTMODE, bool DOROPE>
__global__ __launch_bounds__(512, 2) void gemm256(const u16* __restrict__ A,
    const u16* __restrict__ BT, void* __restrict__ Cv,
    const float* __restrict__ FC, const float* __restrict__ FS,
    int M, int N, int K) {
  extern __shared__ __attribute__((aligned(16))) u16 DL[];  // 3 x 16384 u16
  const int tid = threadIdx.x;
  const int nbx = N >> 8;
  const int cpx = gridDim.x >> 3;                 // grid % 8 == 0
  const int swzb = (blockIdx.x & 7) * cpx + (blockIdx.x >> 3);
  const int bn0 = (swzb % nbx) << 8, bm0 = (swzb / nbx) << 8;
  const int l = tid & 63, g = l >> 4, q = l & 15;
  const int w = tid >> 6;
  const int wm = (w >> 2) * 128, wn = (w & 3) * 64;
  const int nt = K >> 5;   // BK = 32
  f32x4 acc[8][4] = {};

  const int srow = tid >> 2, schunk = tid & 3;
  const int ssw = (schunk ^ ((srow >> 1) & 3)) << 3;
  const u16* gA0 = A  + (size_t)(bm0 + srow) * K + ssw;
  const u16* gA1 = gA0 + (size_t)128 * K;
  const u16* gB0 = BT + (size_t)(bn0 + srow) * K + ssw;
  const u16* gB1 = gB0 + (size_t)128 * K;

  auto STAGE = [&](int t) {
    const int kt = t << 5;
    u16* d = DL + (t % 3) * 16384;
    GLDS16(gA0 + kt, d + tid * 8);
    GLDS16(gA1 + kt, d + 4096 + tid * 8);
    GLDS16(gB0 + kt, d + 8192 + tid * 8);
    GLDS16(gB1 + kt, d + 12288 + tid * 8);
  };

  const u16* ra = DL + (wm + q) * 32 + ((g ^ (((wm + q) >> 1) & 3)) << 3);
  const u16* rb = DL + 8192 + (wn + q) * 32 + ((g ^ (((wn + q) >> 1) & 3)) << 3);

  bf16x8 aC[8], aN[8], bC[4], bN[4];

  STAGE(0); STAGE(1);
  asm volatile("s_waitcnt vmcnt(4)" ::: "memory");
  __builtin_amdgcn_s_barrier();
  #pragma unroll
  for (int m = 0; m < 8; ++m) aC[m] = *(const bf16x8*)(ra + m * 512);
  #pragma unroll
  for (int n = 0; n < 4; ++n) bC[n] = *(const bf16x8*)(rb + n * 512);

  auto TILE = [&](int t, bf16x8 (&ac)[8], bf16x8 (&bc)[4],
                         bf16x8 (&an)[8], bf16x8 (&bn)[4]) {
    if (t + 2 < nt) {
      STAGE(t + 2);
      asm volatile("s_waitcnt vmcnt(4)" ::: "memory");
    } else {
      asm volatile("s_waitcnt vmcnt(0)" ::: "memory");
    }
    __builtin_amdgcn_s_barrier();
    if (t + 1 < nt) {
      const u16* pa = ra + ((t + 1) % 3) * 16384;
      const u16* pb = rb + ((t + 1) % 3) * 16384;
      #pragma unroll
      for (int m = 0; m < 8; ++m) an[m] = *(const bf16x8*)(pa + m * 512);
      #pragma unroll
      for (int n = 0; n < 4; ++n) bn[n] = *(const bf16x8*)(pb + n * 512);
    }
    __builtin_amdgcn_s_setprio(1);
    #pragma unroll
    for (int m = 0; m < 8; ++m) {
      acc[m][0] = mfma16(ac[m], bc[0], acc[m][0]);
      acc[m][1] = mfma16(ac[m], bc[1], acc[m][1]);
      acc[m][2] = mfma16(ac[m], bc[2], acc[m][2]);
      acc[m][3] = mfma16(ac[m], bc[3], acc[m][3]);
    }
    __builtin_amdgcn_s_setprio(0);
  };

  for (int t = 0; t < nt; t += 2) {
    TILE(t,     aC, bC, aN, bN);
    TILE(t + 1, aN, bN, aC, bC);
  }

  #pragma unroll
  for (int m = 0; m < 8; ++m)
    #pragma unroll
    for (int n = 0; n < 4; ++n) {
      const int col = bn0 + wn + n * 16 + q;
      if (DOROPE) {
        const int fi = (col & 127) >> 1;
        const float sgn = (q & 1) ? 1.0f : -1.0f;
        #pragma unroll
        for (int j = 0; j < 4; ++j) {
          int row = bm0 + wm + m * 16 + g * 4 + j;
          int pos = row & (S_ - 1);
          float c = FC[pos * 64 + fi], s = FS[pos * 64 + fi];
          float own = acc[m][n][j];
          float par = __shfl_xor(own, 1);
          ((u16*)Cv)[(size_t)row * N + col] = f2bf(own * c + par * s * sgn);
        }
      } else {
        #pragma unroll
        for (int j = 0; j < 4; ++j) {
          size_t off = (size_t)(bm0 + wm + m * 16 + g * 4 + j) * N + col;
          if (OUTMODE == 1) ((float*)Cv)[off] = acc[m][n][j];
          else              ((u16*)Cv)[off]  = f2bf(acc[m][n][j]);
        }
      }
    }
}

// ------- KV projection GEMM: BM=256 x BN=128, 3-buf reg pipeline -------
// K branch (col<1024): fused RoPE (lane-pair shfl). V branch: tiled V^T layout.
__global__ __launch_bounds__(512, 2) void gemm_kv(const u16* __restrict__ A,
    const u16* __restrict__ BT, u16* __restrict__ Ck, u16* __restrict__ Cvt,
    const float* __restrict__ FC, const float* __restrict__ FS,
    int M, int N, int K) {
  extern __shared__ __attribute__((aligned(16))) u16 DL[];  // 3 x 12288 u16
  const int tid = threadIdx.x;
  const int nbx = N >> 7;                          // 16
  const int cpx = gridDim.x >> 3;
  const int swzb = (blockIdx.x & 7) * cpx + (blockIdx.x >> 3);
  const int bn0 = (swzb % nbx) << 7, bm0 = (swzb / nbx) << 8;
  const int l = tid & 63, g = l >> 4, q = l & 15;
  const int w = tid >> 6;
  const int wm = (w >> 2) * 128, wn = (w & 3) * 32;
  const int nt = K >> 5;
  f32x4 acc[8][2] = {};

  const int srow = tid >> 2, schunk = tid & 3;
  const int ssw = (schunk ^ ((srow >> 1) & 3)) << 3;
  const u16* gA0 = A  + (size_t)(bm0 + srow) * K + ssw;
  const u16* gA1 = gA0 + (size_t)128 * K;
  const u16* gB0 = BT + (size_t)(bn0 + srow) * K + ssw;

  auto STAGE = [&](int t) {
    const int kt = t << 5;
    u16* d = DL + (t % 3) * 12288;
    GLDS16(gA0 + kt, d + tid * 8);
    GLDS16(gA1 + kt, d + 4096 + tid * 8);
    GLDS16(gB0 + kt, d + 8192 + tid * 8);
  };

  const u16* ra = DL + (wm + q) * 32 + ((g ^ (((wm + q) >> 1) & 3)) << 3);
  const u16* rb = DL + 8192 + (wn + q) * 32 + ((g ^ (((wn + q) >> 1) & 3)) << 3);

  bf16x8 aC[8], aN[8], bC[2], bN[2];

  STAGE(0); STAGE(1);
  asm volatile("s_waitcnt vmcnt(3)" ::: "memory");
  __builtin_amdgcn_s_barrier();
  #pragma unroll
  for (int m = 0; m < 8; ++m) aC[m] = *(const bf16x8*)(ra + m * 512);
  #pragma unroll
  for (int n = 0; n < 2; ++n) bC[n] = *(const bf16x8*)(rb + n * 512);

  auto TILE = [&](int t, bf16x8 (&ac)[8], bf16x8 (&bc)[2],
                         bf16x8 (&an)[8], bf16x8 (&bn)[2]) {
    if (t + 2 < nt) {
      STAGE(t + 2);
      asm volatile("s_waitcnt vmcnt(3)" ::: "memory");
    } else {
      asm volatile("s_waitcnt vmcnt(0)" ::: "memory");
    }
    __builtin_amdgcn_s_barrier();
    if (t + 1 < nt) {
      const u16* pa = ra + ((t + 1) % 3) * 12288;
      const u16* pb = rb + ((t + 1) % 3) * 12288;
      #pragma unroll
      for (int m = 0; m < 8; ++m) an[m] = *(const bf16x8*)(pa + m * 512);
      #pragma unroll
      for (int n = 0; n < 2; ++n) bn[n] = *(const bf16x8*)(pb + n * 512);
    }
    __builtin_amdgcn_s_setprio(1);
    #pragma unroll
    for (int m = 0; m < 8; ++m) {
      acc[m][0] = mfma16(ac[m], bc[0], acc[m][0]);
      acc[m][1] = mfma16(ac[m], bc[1], acc[m][1]);
    }
    __builtin_amdgcn_s_setprio(0);
  };

  for (int t = 0; t < nt; t += 2) {
    TILE(t,     aC, bC, aN, bN);
    TILE(t + 1, aN, bN, aC, bC);
  }

  #pragma unroll
  for (int m = 0; m < 8; ++m)
    #pragma unroll
    for (int n = 0; n < 2; ++n) {
      int row0 = bm0 + wm + m * 16 + g * 4;
      int col  = bn0 + wn + n * 16 + q;
      if (col < 1024) {       // K head-cols: apply RoPE (uniform per 16-lane blk)
        const int fi = (col & 127) >> 1;
        const float sgn = (q & 1) ? 1.0f : -1.0f;
        #pragma unroll
        for (int j = 0; j < 4; ++j) {
          int row = row0 + j;
          int pos = row & (S_ - 1);
          float c = FC[pos * 64 + fi], s = FS[pos * 64 + fi];
          float own = acc[m][n][j];
          float par = __shfl_xor(own, 1);
          Ck[(size_t)row * 1024 + col] = f2bf(own * c + par * s * sgn);
        }
      } else {
        int c2 = col - 1024;
        u16x4 pk;
        #pragma unroll
        for (int j = 0; j < 4; ++j) pk[j] = f2bf(acc[m][n][j]);
        size_t off = ((size_t)((row0 >> 11) * KV_ + (c2 >> 7)) * 32 + ((row0 >> 6) & 31)) * 8192
                   + (size_t)(c2 & 127) * 64 + (row0 & 63);
        *(u16x4*)(Cvt + off) = pk;
      }
    }
}

// ---------------- causal GQA flash attention (swapped-QK^T) ----------------
// R11 version (138us measured). grid (16,H,B)=1024 blocks=4/CU; 4 waves;
// QT=64 (16 q-rows/wave), pairing {31-p, p} -> uniform 33 KT=64 iters/block.
// Lessons: launch_bounds arg2 caps VGPR at 512/N (R12: (256,8)=32 VGPR=spill);
// grid=capacity kills backfill (R13). Pairing at 4 blocks/CU is the optimum.
__global__ __launch_bounds__(256, 4) void attn_kernel(
    const u16* __restrict__ Qb, const u16* __restrict__ Kb,
    const u16* __restrict__ VTg, u16* __restrict__ Ob) {
  __shared__ __attribute__((aligned(16))) u16 SM[20480]; // 40KB
  u16* Ks = SM;            // [64][128] swz(row&7)
  u16* Vs = SM + 8192;     // [128][64] swz(row&7)
  u16* Ps = SM + 16384;    // 4 waves x [16 q][64 k], 16B-chunk ^ (q&7)
  const int pr = blockIdx.x;            // 0..15
  const int h = blockIdx.y, b = blockIdx.z;
  const int kvh = h >> 2;               // N_REP = 4
  const int tid = threadIdx.x, w = tid >> 6, l = tid & 63, g = l >> 4, ql = l & 15;
  const float SL2E = 0.08838834764831845f * 1.4426950408889634f;
  const u16* Qh = Qb + (size_t)b * S_ * NQ_ + h * HD_;
  const u16* Kh = Kb + ((size_t)b * S_ * KV_ + kvh) * HD_;
  const u16* Vh = VTg + (size_t)(b * KV_ + kvh) * (32 * 8192);
  u16* Oh = Ob + (size_t)b * S_ * NQ_ + h * HD_;

  for (int ph = 0; ph < 2; ++ph) {
    const int qt = ph ? pr : 31 - pr;
    __syncthreads();   // SM (epilogue scratch) free before restaging
    bf16x8 aq[4];
    #pragma unroll
    for (int kk = 0; kk < 4; ++kk)
      aq[kk] = *(const bf16x8*)(Qh + (size_t)(qt * 64 + w * 16 + ql) * NQ_ + kk * 32 + g * 8);

    f32x4 o[8] = {};
    float mrow = -3.0e38f, lrow = 0.f;

    const int nkt = qt + 1;
    for (int kt = 0; kt < nkt; ++kt) {
      #pragma unroll
      for (int p = 0; p < 4; ++p) {   // K: [64][128]
        int c = tid + p * 256;
        int row = c >> 4, slot = c & 15;
        GLDS16(Kh + (size_t)(kt * 64 + row) * (KV_ * HD_) + ((slot ^ (row & 7)) << 3), Ks + c * 8);
      }
      #pragma unroll
      for (int p = 0; p < 4; ++p) {   // V^T: [128][64] from contiguous 16KB tile
        int c = tid + p * 256;
        int row = c >> 3, slot = c & 7;
        GLDS16(Vh + (size_t)kt * 8192 + row * 64 + ((slot ^ (row & 7)) << 3), Vs + c * 8);
      }
      asm volatile("s_waitcnt vmcnt(0)" ::: "memory");
      __builtin_amdgcn_s_barrier();

      if (kt * 64 <= qt * 64 + w * 16 + 15) {   // wave-uniform activity gate
        // ---- S^T = K * Q^T ----
        f32x4 sc[4] = {};
        #pragma unroll
        for (int kk = 0; kk < 4; ++kk) {
          bf16x8 bk[4];
          #pragma unroll
          for (int n = 0; n < 4; ++n) {
            int row = n * 16 + ql;
            bk[n] = *(const bf16x8*)(Ks + row * 128 + (((kk * 4 + g) ^ (row & 7)) << 3));
          }
          #pragma unroll
          for (int n = 0; n < 4; ++n)
            sc[n] = mfma16(bk[n], aq[kk], sc[n]);
        }
        // ---- causal mask (diagonal tiles only); lane holds k=kt*64+n*16+g*4+j, q=ql ----
        const int qglob = qt * 64 + w * 16 + ql;
        if (kt * 64 + 63 > qt * 64 + w * 16) {
          #pragma unroll
          for (int n = 0; n < 4; ++n)
            #pragma unroll
            for (int j = 0; j < 4; ++j)
              if (kt * 64 + n * 16 + g * 4 + j > qglob) sc[n][j] = -3.0e38f;
        }
        // ---- online softmax: in-lane over 16 k-vals, then xor16/xor32 ----
        float mx = sc[0][0];
        #pragma unroll
        for (int n = 0; n < 4; ++n)
          #pragma unroll
          for (int j = 0; j < 4; ++j) mx = fmaxf(mx, sc[n][j]);
        mx = fmaxf(mx, __shfl_xor(mx, 16));
        mx = fmaxf(mx, __shfl_xor(mx, 32));
        if (!__all(mx - mrow <= 16.0f)) {      // defer-max: P bounded by 2^2.04
          float mnew = fmaxf(mrow, mx);
          float f = exp2f((mrow - mnew) * SL2E);
          lrow *= f;
          #pragma unroll
          for (int m = 0; m < 8; ++m) o[m] *= f;
          mrow = mnew;
        }
        float rs = 0.f;
        #pragma unroll
        for (int n = 0; n < 4; ++n)
          #pragma unroll
          for (int j = 0; j < 4; ++j) {
            float pv = exp2f((sc[n][j] - mrow) * SL2E);
            sc[n][j] = pv; rs += pv;
          }
        rs += __shfl_xor(rs, 16);
        rs += __shfl_xor(rs, 32);
        lrow += rs;
        // ---- P -> LDS: [16 q][64 k], 16B chunk ^ (q&7); 4 x u16x4 writes ----
        u16* Pw = Ps + w * 1024;
        #pragma unroll
        for (int n = 0; n < 4; ++n) {
          u16x4 pk;
          #pragma unroll
          for (int j = 0; j < 4; ++j) pk[j] = f2bft(sc[n][j]);
          *(u16x4*)(Pw + ql * 64 + (((n * 2 + (g >> 1)) ^ (ql & 7)) << 3) + (g & 1) * 4) = pk;
        }
        // ---- PV: O^T = V^T * P^T ----
        #pragma unroll
        for (int kk2 = 0; kk2 < 2; ++kk2) {
          bf16x8 bp = *(const bf16x8*)(Pw + ql * 64 + (((kk2 * 4 + g) ^ (ql & 7)) << 3));
          #pragma unroll
          for (int m = 0; m < 8; ++m) {
            int row = m * 16 + ql;
            bf16x8 av = *(const bf16x8*)(Vs + row * 64 + (((kk2 * 4 + g) ^ (row & 7)) << 3));
            o[m] = mfma16(av, bp, o[m]);
          }
        }
      }
      __builtin_amdgcn_s_barrier();   // all waves done with Ks/Vs before restage
    }
    // ---- epilogue: normalize (lane-local), transpose via LDS, store ----
    __syncthreads();
    u16* OS = SM; // [64][136]
    float linv = 1.0f / lrow;
    #pragma unroll
    for (int m = 0; m < 8; ++m)
      #pragma unroll
      for (int j = 0; j < 4; ++j)
        OS[(w * 16 + ql) * 136 + m * 16 + g * 4 + j] = f2bf(o[m][j] * linv);
    __syncthreads();
    #pragma unroll
    for (int p = 0; p < 4; ++p) {
      int c = tid + p * 256;
      int row = c >> 4, col8 = c & 15;
      u16x8 d = *(const u16x8*)(OS + row * 136 + col8 * 8);
      *(u16x8*)(Oh + (size_t)(qt * 64 + row) * NQ_ + col8 * 8) = d;
    }
  }
}

extern "C" void kernel_launch(void* const* d_in, const int* in_sizes, int n_in,
                              void* d_out, int out_size, void* d_ws, size_t ws_size,
                              hipStream_t stream) {
  const float* x  = (const float*)d_in[0];
  const float* fc = (const float*)d_in[1];
  const float* fs = (const float*)d_in[2];
  // d_in[3] = mask (causal, applied analytically)
  const float* wq = (const float*)d_in[4];
  const float* wk = (const float*)d_in[5];
  const float* wv = (const float*)d_in[6];
  const float* wo = (const float*)d_in[7];

  char* ws = (char*)d_ws;
  u16* xb  = (u16*)(ws + 0);          // 33554432 B
  u16* wqT = (u16*)(ws + 33554432);   // 33554432
  u16* wkT = (u16*)(ws + 67108864);   // 8388608   (wkT||wvT = [2048][4096])
  u16* wvT = (u16*)(ws + 75497472);   // 8388608
  u16* woT = (u16*)(ws + 83886080);   // 33554432
  u16* qb  = (u16*)(ws + 117440512);  // 33554432
  u16* kb  = (u16*)(ws + 150994944);  // 8388608
  u16* vtg = (u16*)(ws + 159383552);  // 8388608  (V^T tiled: [B][KV][32][128][64])
  u16* ob  = (u16*)(ws + 167772160);  // 33554432  -> total 201326592
  if (ws_size < 201326592u) return;

  cvt_bf16<<<(M_ * D_) / (8 * 256), 256, 0, stream>>>(x, xb, M_ * D_);
  tcvt<<<dim3(NQ_ / 64, D_ / 64), 256, 0, stream>>>(wq, wqT, D_, NQ_);
  tcvt<<<dim3(NKV_ / 64, D_ / 64), 256, 0, stream>>>(wk, wkT, D_, NKV_);
  tcvt<<<dim3(NKV_ / 64, D_ / 64), 256, 0, stream>>>(wv, wvT, D_, NKV_);
  tcvt<<<dim3(D_ / 64, NQ_ / 64), 256, 0, stream>>>(wo, woT, NQ_, D_);

  // Q projection + fused RoPE
  gemm256<0, true><<<(NQ_ / 256) * (M_ / 256), 512, 98304, stream>>>(
      xb, wqT, qb, fc, fs, M_, NQ_, D_);
  // fused K+V projection (K branch: fused RoPE; V: tiled V^T layout)
  gemm_kv<<<(2048 / 128) * (M_ / 256), 512, 73728, stream>>>(
      xb, wkT, kb, vtg, fc, fs, M_, 2048, D_);

  attn_kernel<<<dim3(16, H_, B_), 256, 0, stream>>>(qb, kb, vtg, ob);

  gemm256<1, false><<<(D_ / 256) * (M_ / 256), 512, 98304, stream>>>(
      ob, woT, d_out, fc, fs, M_, D_, NQ_);
}

// Round 18
// 508.694 us; speedup vs baseline: 7.6905x; 1.0086x over previous
//
#include <hip/hip_runtime.h>
#include <stdint.h>

#define B_ 2
#define S_ 2048
#define D_ 4096
#define H_ 32
#define KV_ 8
#define HD_ 128
#define M_ (B_*S_)          // 4096 rows (b*S+s)
#define NQ_ (H_*HD_)        // 4096
#define NKV_ (KV_*HD_)      // 1024

typedef unsigned short u16;
typedef __bf16 bf16x8 __attribute__((ext_vector_type(8)));
typedef float f32x4 __attribute__((ext_vector_type(4)));
typedef u16 u16x8 __attribute__((ext_vector_type(8)));
typedef u16 u16x4 __attribute__((ext_vector_type(4)));

__device__ __forceinline__ u16 f2bf(float f) {
  union { float f; unsigned u; } v; v.f = f;
  unsigned r = v.u + 0x7fffu + ((v.u >> 16) & 1u);
  return (u16)(r >> 16);
}
__device__ __forceinline__ u16 f2bft(float f) {  // truncating (for P; values in [0,4.2])
  union { float f; unsigned u; } v; v.f = f;
  return (u16)(v.u >> 16);
}
__device__ __forceinline__ float bf2f(u16 u) {
  union { unsigned u; float f; } v; v.u = ((unsigned)u) << 16;
  return v.f;
}
__device__ __forceinline__ f32x4 mfma16(bf16x8 a, bf16x8 b, f32x4 c) {
  return __builtin_amdgcn_mfma_f32_16x16x32_bf16(a, b, c, 0, 0, 0);
}

#define GLDS16(gp, lp) __builtin_amdgcn_global_load_lds( \
    (const __attribute__((address_space(1))) unsigned int*)(gp), \
    (__attribute__((address_space(3))) unsigned int*)(lp), 16, 0, 0)

// ---------------- fp32 -> bf16 convert (vectorized) ----------------
__global__ __launch_bounds__(256) void cvt_bf16(const float* __restrict__ in,
                                                u16* __restrict__ out, int n) {
  int i = (blockIdx.x * 256 + threadIdx.x) * 8;
  if (i >= n) return;
  float4 a = *(const float4*)(in + i);
  float4 b = *(const float4*)(in + i + 4);
  u16x8 o;
  o[0]=f2bf(a.x); o[1]=f2bf(a.y); o[2]=f2bf(a.z); o[3]=f2bf(a.w);
  o[4]=f2bf(b.x); o[5]=f2bf(b.y); o[6]=f2bf(b.z); o[7]=f2bf(b.w);
  *(u16x8*)(out + i) = o;
}

// -------- transpose + convert: out[c][r] = in[r][c], 64x64, vectorized --------
__global__ __launch_bounds__(256) void tcvt(const float* __restrict__ in,
                                            u16* __restrict__ out, int R, int C) {
  __shared__ float tf[64][65];
  int c0 = blockIdx.x * 64, r0 = blockIdx.y * 64;
  int l16 = threadIdx.x & 15, r16 = threadIdx.x >> 4;
  #pragma unroll
  for (int p = 0; p < 4; ++p) {
    int r = p * 16 + r16;
    float4 v = *(const float4*)(in + (size_t)(r0 + r) * C + c0 + l16 * 4);
    tf[r][l16 * 4 + 0] = v.x; tf[r][l16 * 4 + 1] = v.y;
    tf[r][l16 * 4 + 2] = v.z; tf[r][l16 * 4 + 3] = v.w;
  }
  __syncthreads();
  int oc = threadIdx.x >> 2, ch = threadIdx.x & 3;
  u16x8 o1, o2;
  #pragma unroll
  for (int i = 0; i < 8; ++i) o1[i] = f2bf(tf[ch * 16 + i][oc]);
  #pragma unroll
  for (int i = 0; i < 8; ++i) o2[i] = f2bf(tf[ch * 16 + 8 + i][oc]);
  *(u16x8*)(out + (size_t)(c0 + oc) * R + r0 + ch * 16) = o1;
  *(u16x8*)(out + (size_t)(c0 + oc) * R + r0 + ch * 16 + 8) = o2;
}

// ------- 256x256 GEMM, m201-style 8-phase (4 phases/K-step), BK=64, 2 dbufs -------
// Per K-step t: P1 {b all (8 b128) + a[m0,m1] (4); stage A-half0(t+1); bar;
// lgkm0; 16 MFMA; bar}  P2 {a[m2,m3]; stage A-half1(t+1); ...}  P3 {a[m4,m5];
// stage B-half0(t+2); ...}  P4 {a[m6,m7]; stage B-half1(t+2); gate vmcnt(4);
// bar}. Safety: A(t+1) -> buf (t+1)&1 whose old tile (t-1) fully read by its
// step-end barrier; B(t+2) -> buf t&1, whose B(t) reads all completed once any
// wave passes P1 (phase barrier + lgkm before MFMA). Gate stack at P4:
// [B(t+1), A(t+1), B(t+2)] -> vmcnt(4) completes oldest 8, never drains.
// R16 LESSON kept: straight-line phase bodies, unconditional register writes.
template<int OUTMODE, bool DOROPE>
__global__ __launch_bounds__(512, 2) void gemm256(const u16* __restrict__ A,
    const u16* __restrict__ BT, void* __restrict__ Cv,
    const float* __restrict__ FC, const float* __restrict__ FS,
    int M, int N, int K) {
  extern __shared__ __attribute__((aligned(16))) u16 DL[];  // 2 x (A 16384 + B 16384) u16 = 128KB
  const int tid = threadIdx.x;
  const int nbx = N >> 8;
  const int cpx = gridDim.x >> 3;                 // grid % 8 == 0
  const int swzb = (blockIdx.x & 7) * cpx + (blockIdx.x >> 3);
  const int bn0 = (swzb % nbx) << 8, bm0 = (swzb / nbx) << 8;
  const int l = tid & 63, g = l >> 4, q = l & 15;
  const int w = tid >> 6;
  const int wm = (w >> 2) * 128, wn = (w & 3) * 64;
  const int nt = K >> 6;   // BK = 64
  f32x4 acc[8][4] = {};

  // staging: 512 thr x 16B covers 64 rows x 64k; row = j*64 + (tid>>3),
  // chunk = tid&7, source k pre-swizzled: chunk ^ (row&7) (row&7 = (tid>>3)&7).
  const int srow = tid >> 3, slot = tid & 7;
  const int ssw = (slot ^ (srow & 7)) << 3;
  const u16* gA = A  + (size_t)(bm0 + srow) * K + ssw;
  const u16* gB = BT + (size_t)(bn0 + srow) * K + ssw;

  // stage half h (rows h*128..h*128+127) of operand (oB) for tile t
  auto STG = [&](const u16* gbase, int oB, int h, int t) {
    const int kt = t << 6;
    u16* d = DL + (t & 1) * 32768 + oB * 16384 + h * 8192 + tid * 8;
    GLDS16(gbase + (size_t)(h * 128) * K + kt, d);
    GLDS16(gbase + (size_t)(h * 128 + 64) * K + kt, d + 4096);
  };

  // fragment read bases (chunk = (kk*4+g) ^ (q&7); row&7 == q&7)
  const u16* ra0 = DL + (wm + q) * 64 + ((g ^ (q & 7)) << 3);
  const u16* ra1 = DL + (wm + q) * 64 + (((4 + g) ^ (q & 7)) << 3);
  const u16* rb0 = DL + 16384 + (wn + q) * 64 + ((g ^ (q & 7)) << 3);
  const u16* rb1 = DL + 16384 + (wn + q) * 64 + (((4 + g) ^ (q & 7)) << 3);

  // prologue: A(0), B(0), B(1); wait oldest 8 (tile 0), keep B(1) in flight
  STG(gA, 0, 0, 0); STG(gA, 0, 1, 0);
  STG(gB, 1, 0, 0); STG(gB, 1, 1, 0);
  STG(gB, 1, 0, 1); STG(gB, 1, 1, 1);
  asm volatile("s_waitcnt vmcnt(4)" ::: "memory");
  __builtin_amdgcn_s_barrier();

  for (int t = 0; t < nt; ++t) {
    const int bo = (t & 1) * 32768;
    bf16x8 bf[4][2], ap[2][2];
    // ---- P1: b (all 8) + a[m0,m1]; stage A-half0(t+1) ----
    #pragma unroll
    for (int n = 0; n < 4; ++n) {
      bf[n][0] = *(const bf16x8*)(rb0 + bo + n * 1024);
      bf[n][1] = *(const bf16x8*)(rb1 + bo + n * 1024);
    }
    ap[0][0] = *(const bf16x8*)(ra0 + bo);
    ap[0][1] = *(const bf16x8*)(ra1 + bo);
    ap[1][0] = *(const bf16x8*)(ra0 + bo + 1024);
    ap[1][1] = *(const bf16x8*)(ra1 + bo + 1024);
    if (t + 1 < nt) STG(gA, 0, 0, t + 1);
    __builtin_amdgcn_s_barrier();
    asm volatile("s_waitcnt lgkmcnt(0)" ::: "memory");
    __builtin_amdgcn_sched_barrier(0);
    __builtin_amdgcn_s_setprio(1);
    #pragma unroll
    for (int mm = 0; mm < 2; ++mm)
      #pragma unroll
      for (int n = 0; n < 4; ++n) {
        acc[mm][n] = mfma16(ap[mm][0], bf[n][0], acc[mm][n]);
        acc[mm][n] = mfma16(ap[mm][1], bf[n][1], acc[mm][n]);
      }
    __builtin_amdgcn_s_setprio(0);
    __builtin_amdgcn_s_barrier();
    // ---- P2..P4 ----
    #pragma unroll
    for (int p = 1; p < 4; ++p) {
      const int mb = 2 * p;
      ap[0][0] = *(const bf16x8*)(ra0 + bo + mb * 1024);
      ap[0][1] = *(const bf16x8*)(ra1 + bo + mb * 1024);
      ap[1][0] = *(const bf16x8*)(ra0 + bo + (mb + 1) * 1024);
      ap[1][1] = *(const bf16x8*)(ra1 + bo + (mb + 1) * 1024);
      if (p == 1 && t + 1 < nt) STG(gA, 0, 1, t + 1);
      if (p == 2 && t + 2 < nt) STG(gB, 1, 0, t + 2);
      if (p == 3 && t + 2 < nt) STG(gB, 1, 1, t + 2);
      __builtin_amdgcn_s_barrier();
      asm volatile("s_waitcnt lgkmcnt(0)" ::: "memory");
      __builtin_amdgcn_sched_barrier(0);
      __builtin_amdgcn_s_setprio(1);
      #pragma unroll
      for (int mm = 0; mm < 2; ++mm)
        #pragma unroll
        for (int n = 0; n < 4; ++n) {
          acc[mb + mm][n] = mfma16(ap[mm][0], bf[n][0], acc[mb + mm][n]);
          acc[mb + mm][n] = mfma16(ap[mm][1], bf[n][1], acc[mb + mm][n]);
        }
      __builtin_amdgcn_s_setprio(0);
      if (p < 3) __builtin_amdgcn_s_barrier();
    }
    // ---- step gate: publish tile t+1 ----
    if (t + 1 < nt) {
      if (t + 2 < nt) {
        asm volatile("s_waitcnt vmcnt(4)" ::: "memory");  // B(t+1),A(t+1) done
      } else {
        asm volatile("s_waitcnt vmcnt(0)" ::: "memory");
      }
      __builtin_amdgcn_s_barrier();
    }
  }

  #pragma unroll
  for (int m = 0; m < 8; ++m)
    #pragma unroll
    for (int n = 0; n < 4; ++n) {
      const int col = bn0 + wn + n * 16 + q;
      if (DOROPE) {
        const int fi = (col & 127) >> 1;
        const float sgn = (q & 1) ? 1.0f : -1.0f;
        #pragma unroll
        for (int j = 0; j < 4; ++j) {
          int row = bm0 + wm + m * 16 + g * 4 + j;
          int pos = row & (S_ - 1);
          float c = FC[pos * 64 + fi], s = FS[pos * 64 + fi];
          float own = acc[m][n][j];
          float par = __shfl_xor(own, 1);
          ((u16*)Cv)[(size_t)row * N + col] = f2bf(own * c + par * s * sgn);
        }
      } else {
        #pragma unroll
        for (int j = 0; j < 4; ++j) {
          size_t off = (size_t)(bm0 + wm + m * 16 + g * 4 + j) * N + col;
          if (OUTMODE == 1) ((float*)Cv)[off] = acc[m][n][j];
          else              ((u16*)Cv)[off]  = f2bf(acc[m][n][j]);
        }
      }
    }
}

// ------- KV projection GEMM: BM=256 x BN=128, 3-buf reg pipeline (R10) -------
// K branch (col<1024): fused RoPE (lane-pair shfl). V branch: tiled V^T layout.
__global__ __launch_bounds__(512, 2) void gemm_kv(const u16* __restrict__ A,
    const u16* __restrict__ BT, u16* __restrict__ Ck, u16* __restrict__ Cvt,
    const float* __restrict__ FC, const float* __restrict__ FS,
    int M, int N, int K) {
  extern __shared__ __attribute__((aligned(16))) u16 DL[];  // 3 x 12288 u16
  const int tid = threadIdx.x;
  const int nbx = N >> 7;                          // 16
  const int cpx = gridDim.x >> 3;
  const int swzb = (blockIdx.x & 7) * cpx + (blockIdx.x >> 3);
  const int bn0 = (swzb % nbx) << 7, bm0 = (swzb / nbx) << 8;
  const int l = tid & 63, g = l >> 4, q = l & 15;
  const int w = tid >> 6;
  const int wm = (w >> 2) * 128, wn = (w & 3) * 32;
  const int nt = K >> 5;
  f32x4 acc[8][2] = {};

  const int srow = tid >> 2, schunk = tid & 3;
  const int ssw = (schunk ^ ((srow >> 1) & 3)) << 3;
  const u16* gA0 = A  + (size_t)(bm0 + srow) * K + ssw;
  const u16* gA1 = gA0 + (size_t)128 * K;
  const u16* gB0 = BT + (size_t)(bn0 + srow) * K + ssw;

  auto STAGE = [&](int t) {
    const int kt = t << 5;
    u16* d = DL + (t % 3) * 12288;
    GLDS16(gA0 + kt, d + tid * 8);
    GLDS16(gA1 + kt, d + 4096 + tid * 8);
    GLDS16(gB0 + kt, d + 8192 + tid * 8);
  };

  const u16* ra = DL + (wm + q) * 32 + ((g ^ (((wm + q) >> 1) & 3)) << 3);
  const u16* rb = DL + 8192 + (wn + q) * 32 + ((g ^ (((wn + q) >> 1) & 3)) << 3);

  bf16x8 aC[8], aN[8], bC[2], bN[2];

  STAGE(0); STAGE(1);
  asm volatile("s_waitcnt vmcnt(3)" ::: "memory");
  __builtin_amdgcn_s_barrier();
  #pragma unroll
  for (int m = 0; m < 8; ++m) aC[m] = *(const bf16x8*)(ra + m * 512);
  #pragma unroll
  for (int n = 0; n < 2; ++n) bC[n] = *(const bf16x8*)(rb + n * 512);

  auto TILE = [&](int t, bf16x8 (&ac)[8], bf16x8 (&bc)[2],
                         bf16x8 (&an)[8], bf16x8 (&bn)[2]) {
    if (t + 2 < nt) {
      STAGE(t + 2);
      asm volatile("s_waitcnt vmcnt(3)" ::: "memory");
    } else {
      asm volatile("s_waitcnt vmcnt(0)" ::: "memory");
    }
    __builtin_amdgcn_s_barrier();
    if (t + 1 < nt) {
      const u16* pa = ra + ((t + 1) % 3) * 12288;
      const u16* pb = rb + ((t + 1) % 3) * 12288;
      #pragma unroll
      for (int m = 0; m < 8; ++m) an[m] = *(const bf16x8*)(pa + m * 512);
      #pragma unroll
      for (int n = 0; n < 2; ++n) bn[n] = *(const bf16x8*)(pb + n * 512);
    }
    __builtin_amdgcn_s_setprio(1);
    #pragma unroll
    for (int m = 0; m < 8; ++m) {
      acc[m][0] = mfma16(ac[m], bc[0], acc[m][0]);
      acc[m][1] = mfma16(ac[m], bc[1], acc[m][1]);
    }
    __builtin_amdgcn_s_setprio(0);
  };

  for (int t = 0; t < nt; t += 2) {
    TILE(t,     aC, bC, aN, bN);
    TILE(t + 1, aN, bN, aC, bC);
  }

  #pragma unroll
  for (int m = 0; m < 8; ++m)
    #pragma unroll
    for (int n = 0; n < 2; ++n) {
      int row0 = bm0 + wm + m * 16 + g * 4;
      int col  = bn0 + wn + n * 16 + q;
      if (col < 1024) {       // K head-cols: apply RoPE (uniform per 16-lane blk)
        const int fi = (col & 127) >> 1;
        const float sgn = (q & 1) ? 1.0f : -1.0f;
        #pragma unroll
        for (int j = 0; j < 4; ++j) {
          int row = row0 + j;
          int pos = row & (S_ - 1);
          float c = FC[pos * 64 + fi], s = FS[pos * 64 + fi];
          float own = acc[m][n][j];
          float par = __shfl_xor(own, 1);
          Ck[(size_t)row * 1024 + col] = f2bf(own * c + par * s * sgn);
        }
      } else {
        int c2 = col - 1024;
        u16x4 pk;
        #pragma unroll
        for (int j = 0; j < 4; ++j) pk[j] = f2bf(acc[m][n][j]);
        size_t off = ((size_t)((row0 >> 11) * KV_ + (c2 >> 7)) * 32 + ((row0 >> 6) & 31)) * 8192
                   + (size_t)(c2 & 127) * 64 + (row0 & 63);
        *(u16x4*)(Cvt + off) = pk;
      }
    }
}

// ---------------- causal GQA flash attention (swapped-QK^T) ----------------
// R11 version (138us measured). grid (16,H,B)=1024 blocks=4/CU; 4 waves;
// QT=64 (16 q-rows/wave), pairing {31-p, p} -> uniform 33 KT=64 iters/block.
// Lessons: launch_bounds arg2 caps VGPR at 512/N (R12: (256,8)=32 VGPR=spill);
// grid=capacity kills backfill (R13). Pairing at 4 blocks/CU is the optimum.
__global__ __launch_bounds__(256, 4) void attn_kernel(
    const u16* __restrict__ Qb, const u16* __restrict__ Kb,
    const u16* __restrict__ VTg, u16* __restrict__ Ob) {
  __shared__ __attribute__((aligned(16))) u16 SM[20480]; // 40KB
  u16* Ks = SM;            // [64][128] swz(row&7)
  u16* Vs = SM + 8192;     // [128][64] swz(row&7)
  u16* Ps = SM + 16384;    // 4 waves x [16 q][64 k], 16B-chunk ^ (q&7)
  const int pr = blockIdx.x;            // 0..15
  const int h = blockIdx.y, b = blockIdx.z;
  const int kvh = h >> 2;               // N_REP = 4
  const int tid = threadIdx.x, w = tid >> 6, l = tid & 63, g = l >> 4, ql = l & 15;
  const float SL2E = 0.08838834764831845f * 1.4426950408889634f;
  const u16* Qh = Qb + (size_t)b * S_ * NQ_ + h * HD_;
  const u16* Kh = Kb + ((size_t)b * S_ * KV_ + kvh) * HD_;
  const u16* Vh = VTg + (size_t)(b * KV_ + kvh) * (32 * 8192);
  u16* Oh = Ob + (size_t)b * S_ * NQ_ + h * HD_;

  for (int ph = 0; ph < 2; ++ph) {
    const int qt = ph ? pr : 31 - pr;
    __syncthreads();   // SM (epilogue scratch) free before restaging
    bf16x8 aq[4];
    #pragma unroll
    for (int kk = 0; kk < 4; ++kk)
      aq[kk] = *(const bf16x8*)(Qh + (size_t)(qt * 64 + w * 16 + ql) * NQ_ + kk * 32 + g * 8);

    f32x4 o[8] = {};
    float mrow = -3.0e38f, lrow = 0.f;

    const int nkt = qt + 1;
    for (int kt = 0; kt < nkt; ++kt) {
      #pragma unroll
      for (int p = 0; p < 4; ++p) {   // K: [64][128]
        int c = tid + p * 256;
        int row = c >> 4, slot = c & 15;
        GLDS16(Kh + (size_t)(kt * 64 + row) * (KV_ * HD_) + ((slot ^ (row & 7)) << 3), Ks + c * 8);
      }
      #pragma unroll
      for (int p = 0; p < 4; ++p) {   // V^T: [128][64] from contiguous 16KB tile
        int c = tid + p * 256;
        int row = c >> 3, slot = c & 7;
        GLDS16(Vh + (size_t)kt * 8192 + row * 64 + ((slot ^ (row & 7)) << 3), Vs + c * 8);
      }
      asm volatile("s_waitcnt vmcnt(0)" ::: "memory");
      __builtin_amdgcn_s_barrier();

      if (kt * 64 <= qt * 64 + w * 16 + 15) {   // wave-uniform activity gate
        // ---- S^T = K * Q^T ----
        f32x4 sc[4] = {};
        #pragma unroll
        for (int kk = 0; kk < 4; ++kk) {
          bf16x8 bk[4];
          #pragma unroll
          for (int n = 0; n < 4; ++n) {
            int row = n * 16 + ql;
            bk[n] = *(const bf16x8*)(Ks + row * 128 + (((kk * 4 + g) ^ (row & 7)) << 3));
          }
          #pragma unroll
          for (int n = 0; n < 4; ++n)
            sc[n] = mfma16(bk[n], aq[kk], sc[n]);
        }
        // ---- causal mask (diagonal tiles only); lane holds k=kt*64+n*16+g*4+j, q=ql ----
        const int qglob = qt * 64 + w * 16 + ql;
        if (kt * 64 + 63 > qt * 64 + w * 16) {
          #pragma unroll
          for (int n = 0; n < 4; ++n)
            #pragma unroll
            for (int j = 0; j < 4; ++j)
              if (kt * 64 + n * 16 + g * 4 + j > qglob) sc[n][j] = -3.0e38f;
        }
        // ---- online softmax: in-lane over 16 k-vals, then xor16/xor32 ----
        float mx = sc[0][0];
        #pragma unroll
        for (int n = 0; n < 4; ++n)
          #pragma unroll
          for (int j = 0; j < 4; ++j) mx = fmaxf(mx, sc[n][j]);
        mx = fmaxf(mx, __shfl_xor(mx, 16));
        mx = fmaxf(mx, __shfl_xor(mx, 32));
        if (!__all(mx - mrow <= 16.0f)) {      // defer-max: P bounded by 2^2.04
          float mnew = fmaxf(mrow, mx);
          float f = exp2f((mrow - mnew) * SL2E);
          lrow *= f;
          #pragma unroll
          for (int m = 0; m < 8; ++m) o[m] *= f;
          mrow = mnew;
        }
        float rs = 0.f;
        #pragma unroll
        for (int n = 0; n < 4; ++n)
          #pragma unroll
          for (int j = 0; j < 4; ++j) {
            float pv = exp2f((sc[n][j] - mrow) * SL2E);
            sc[n][j] = pv; rs += pv;
          }
        rs += __shfl_xor(rs, 16);
        rs += __shfl_xor(rs, 32);
        lrow += rs;
        // ---- P -> LDS: [16 q][64 k], 16B chunk ^ (q&7); 4 x u16x4 writes ----
        u16* Pw = Ps + w * 1024;
        #pragma unroll
        for (int n = 0; n < 4; ++n) {
          u16x4 pk;
          #pragma unroll
          for (int j = 0; j < 4; ++j) pk[j] = f2bft(sc[n][j]);
          *(u16x4*)(Pw + ql * 64 + (((n * 2 + (g >> 1)) ^ (ql & 7)) << 3) + (g & 1) * 4) = pk;
        }
        // ---- PV: O^T = V^T * P^T ----
        #pragma unroll
        for (int kk2 = 0; kk2 < 2; ++kk2) {
          bf16x8 bp = *(const bf16x8*)(Pw + ql * 64 + (((kk2 * 4 + g) ^ (ql & 7)) << 3));
          #pragma unroll
          for (int m = 0; m < 8; ++m) {
            int row = m * 16 + ql;
            bf16x8 av = *(const bf16x8*)(Vs + row * 64 + (((kk2 * 4 + g) ^ (row & 7)) << 3));
            o[m] = mfma16(av, bp, o[m]);
          }
        }
      }
      __builtin_amdgcn_s_barrier();   // all waves done with Ks/Vs before restage
    }
    // ---- epilogue: normalize (lane-local), transpose via LDS, store ----
    __syncthreads();
    u16* OS = SM; // [64][136]
    float linv = 1.0f / lrow;
    #pragma unroll
    for (int m = 0; m < 8; ++m)
      #pragma unroll
      for (int j = 0; j < 4; ++j)
        OS[(w * 16 + ql) * 136 + m * 16 + g * 4 + j] = f2bf(o[m][j] * linv);
    __syncthreads();
    #pragma unroll
    for (int p = 0; p < 4; ++p) {
      int c = tid + p * 256;
      int row = c >> 4, col8 = c & 15;
      u16x8 d = *(const u16x8*)(OS + row * 136 + col8 * 8);
      *(u16x8*)(Oh + (size_t)(qt * 64 + row) * NQ_ + col8 * 8) = d;
    }
  }
}

extern "C" void kernel_launch(void* const* d_in, const int* in_sizes, int n_in,
                              void* d_out, int out_size, void* d_ws, size_t ws_size,
                              hipStream_t stream) {
  const float* x  = (const float*)d_in[0];
  const float* fc = (const float*)d_in[1];
  const float* fs = (const float*)d_in[2];
  // d_in[3] = mask (causal, applied analytically)
  const float* wq = (const float*)d_in[4];
  const float* wk = (const float*)d_in[5];
  const float* wv = (const float*)d_in[6];
  const float* wo = (const float*)d_in[7];

  char* ws = (char*)d_ws;
  u16* xb  = (u16*)(ws + 0);          // 33554432 B
  u16* wqT = (u16*)(ws + 33554432);   // 33554432
  u16* wkT = (u16*)(ws + 67108864);   // 8388608   (wkT||wvT = [2048][4096])
  u16* wvT = (u16*)(ws + 75497472);   // 8388608
  u16* woT = (u16*)(ws + 83886080);   // 33554432
  u16* qb  = (u16*)(ws + 117440512);  // 33554432
  u16* kb  = (u16*)(ws + 150994944);  // 8388608
  u16* vtg = (u16*)(ws + 159383552);  // 8388608  (V^T tiled: [B][KV][32][128][64])
  u16* ob  = (u16*)(ws + 167772160);  // 33554432  -> total 201326592
  if (ws_size < 201326592u) return;

  cvt_bf16<<<(M_ * D_) / (8 * 256), 256, 0, stream>>>(x, xb, M_ * D_);
  tcvt<<<dim3(NQ_ / 64, D_ / 64), 256, 0, stream>>>(wq, wqT, D_, NQ_);
  tcvt<<<dim3(NKV_ / 64, D_ / 64), 256, 0, stream>>>(wk, wkT, D_, NKV_);
  tcvt<<<dim3(NKV_ / 64, D_ / 64), 256, 0, stream>>>(wv, wvT, D_, NKV_);
  tcvt<<<dim3(D_ / 64, NQ_ / 64), 256, 0, stream>>>(wo, woT, NQ_, D_);

  // Q projection + fused RoPE (8-phase schedule, 128KB dynamic LDS)
  gemm256<0, true><<<(NQ_ / 256) * (M_ / 256), 512, 131072, stream>>>(
      xb, wqT, qb, fc, fs, M_, NQ_, D_);
  // fused K+V projection (K branch: fused RoPE; V: tiled V^T layout)
  gemm_kv<<<(2048 / 128) * (M_ / 256), 512, 73728, stream>>>(
      xb, wkT, kb, vtg, fc, fs, M_, 2048, D_);

  attn_kernel<<<dim3(16, H_, B_), 256, 0, stream>>>(qb, kb, vtg, ob);

  gemm256<1, false><<<(D_ / 256) * (M_ / 256), 512, 131072, stream>>>(
      ob, woT, d_out, fc, fs, M_, D_, NQ_);
}

// Round 19
// 507.688 us; speedup vs baseline: 7.7058x; 1.0020x over previous
//
#include <hip/hip_runtime.h>
#include <stdint.h>

#define B_ 2
#define S_ 2048
#define D_ 4096
#define H_ 32
#define KV_ 8
#define HD_ 128
#define M_ (B_*S_)          // 4096 rows (b*S+s)
#define NQ_ (H_*HD_)        // 4096
#define NKV_ (KV_*HD_)      // 1024

typedef unsigned short u16;
typedef __bf16 bf16x8 __attribute__((ext_vector_type(8)));
typedef float f32x4 __attribute__((ext_vector_type(4)));
typedef u16 u16x8 __attribute__((ext_vector_type(8)));
typedef u16 u16x4 __attribute__((ext_vector_type(4)));

__device__ __forceinline__ u16 f2bf(float f) {
  union { float f; unsigned u; } v; v.f = f;
  unsigned r = v.u + 0x7fffu + ((v.u >> 16) & 1u);
  return (u16)(r >> 16);
}
__device__ __forceinline__ u16 f2bft(float f) {  // truncating (for P; values in [0,4.2])
  union { float f; unsigned u; } v; v.f = f;
  return (u16)(v.u >> 16);
}
__device__ __forceinline__ float bf2f(u16 u) {
  union { unsigned u; float f; } v; v.u = ((unsigned)u) << 16;
  return v.f;
}
__device__ __forceinline__ f32x4 mfma16(bf16x8 a, bf16x8 b, f32x4 c) {
  return __builtin_amdgcn_mfma_f32_16x16x32_bf16(a, b, c, 0, 0, 0);
}

#define GLDS16(gp, lp) __builtin_amdgcn_global_load_lds( \
    (const __attribute__((address_space(1))) unsigned int*)(gp), \
    (__attribute__((address_space(3))) unsigned int*)(lp), 16, 0, 0)

// ---------------- fp32 -> bf16 convert (vectorized) ----------------
__global__ __launch_bounds__(256) void cvt_bf16(const float* __restrict__ in,
                                                u16* __restrict__ out, int n) {
  int i = (blockIdx.x * 256 + threadIdx.x) * 8;
  if (i >= n) return;
  float4 a = *(const float4*)(in + i);
  float4 b = *(const float4*)(in + i + 4);
  u16x8 o;
  o[0]=f2bf(a.x); o[1]=f2bf(a.y); o[2]=f2bf(a.z); o[3]=f2bf(a.w);
  o[4]=f2bf(b.x); o[5]=f2bf(b.y); o[6]=f2bf(b.z); o[7]=f2bf(b.w);
  *(u16x8*)(out + i) = o;
}

// -------- transpose + convert: out[c][r] = in[r][c], 64x64, vectorized --------
__global__ __launch_bounds__(256) void tcvt(const float* __restrict__ in,
                                            u16* __restrict__ out, int R, int C) {
  __shared__ float tf[64][65];
  int c0 = blockIdx.x * 64, r0 = blockIdx.y * 64;
  int l16 = threadIdx.x & 15, r16 = threadIdx.x >> 4;
  #pragma unroll
  for (int p = 0; p < 4; ++p) {
    int r = p * 16 + r16;
    float4 v = *(const float4*)(in + (size_t)(r0 + r) * C + c0 + l16 * 4);
    tf[r][l16 * 4 + 0] = v.x; tf[r][l16 * 4 + 1] = v.y;
    tf[r][l16 * 4 + 2] = v.z; tf[r][l16 * 4 + 3] = v.w;
  }
  __syncthreads();
  int oc = threadIdx.x >> 2, ch = threadIdx.x & 3;
  u16x8 o1, o2;
  #pragma unroll
  for (int i = 0; i < 8; ++i) o1[i] = f2bf(tf[ch * 16 + i][oc]);
  #pragma unroll
  for (int i = 0; i < 8; ++i) o2[i] = f2bf(tf[ch * 16 + 8 + i][oc]);
  *(u16x8*)(out + (size_t)(c0 + oc) * R + r0 + ch * 16) = o1;
  *(u16x8*)(out + (size_t)(c0 + oc) * R + r0 + ch * 16 + 8) = o2;
}

// ------- 256x256 GEMM, m201-style 8-phase (4 phases/K-step), BK=64, 2 dbufs -------
// (R18; ~equal to 3-buf pipeline, kept. 40-42% MfmaUtil plateau is robust to
// scheduling: coarse/4-phase/8-phase/3-buf all land there.)
template<int OUTMODE, bool DOROPE>
__global__ __launch_bounds__(512, 2) void gemm256(const u16* __restrict__ A,
    const u16* __restrict__ BT, void* __restrict__ Cv,
    const float* __restrict__ FC, const float* __restrict__ FS,
    int M, int N, int K) {
  extern __shared__ __attribute__((aligned(16))) u16 DL[];  // 2 x (A 16384 + B 16384) u16 = 128KB
  const int tid = threadIdx.x;
  const int nbx = N >> 8;
  const int cpx = gridDim.x >> 3;                 // grid % 8 == 0
  const int swzb = (blockIdx.x & 7) * cpx + (blockIdx.x >> 3);
  const int bn0 = (swzb % nbx) << 8, bm0 = (swzb / nbx) << 8;
  const int l = tid & 63, g = l >> 4, q = l & 15;
  const int w = tid >> 6;
  const int wm = (w >> 2) * 128, wn = (w & 3) * 64;
  const int nt = K >> 6;   // BK = 64
  f32x4 acc[8][4] = {};

  const int srow = tid >> 3, slot = tid & 7;
  const int ssw = (slot ^ (srow & 7)) << 3;
  const u16* gA = A  + (size_t)(bm0 + srow) * K + ssw;
  const u16* gB = BT + (size_t)(bn0 + srow) * K + ssw;

  auto STG = [&](const u16* gbase, int oB, int h, int t) {
    const int kt = t << 6;
    u16* d = DL + (t & 1) * 32768 + oB * 16384 + h * 8192 + tid * 8;
    GLDS16(gbase + (size_t)(h * 128) * K + kt, d);
    GLDS16(gbase + (size_t)(h * 128 + 64) * K + kt, d + 4096);
  };

  const u16* ra0 = DL + (wm + q) * 64 + ((g ^ (q & 7)) << 3);
  const u16* ra1 = DL + (wm + q) * 64 + (((4 + g) ^ (q & 7)) << 3);
  const u16* rb0 = DL + 16384 + (wn + q) * 64 + ((g ^ (q & 7)) << 3);
  const u16* rb1 = DL + 16384 + (wn + q) * 64 + (((4 + g) ^ (q & 7)) << 3);

  STG(gA, 0, 0, 0); STG(gA, 0, 1, 0);
  STG(gB, 1, 0, 0); STG(gB, 1, 1, 0);
  STG(gB, 1, 0, 1); STG(gB, 1, 1, 1);
  asm volatile("s_waitcnt vmcnt(4)" ::: "memory");
  __builtin_amdgcn_s_barrier();

  for (int t = 0; t < nt; ++t) {
    const int bo = (t & 1) * 32768;
    bf16x8 bf[4][2], ap[2][2];
    #pragma unroll
    for (int n = 0; n < 4; ++n) {
      bf[n][0] = *(const bf16x8*)(rb0 + bo + n * 1024);
      bf[n][1] = *(const bf16x8*)(rb1 + bo + n * 1024);
    }
    ap[0][0] = *(const bf16x8*)(ra0 + bo);
    ap[0][1] = *(const bf16x8*)(ra1 + bo);
    ap[1][0] = *(const bf16x8*)(ra0 + bo + 1024);
    ap[1][1] = *(const bf16x8*)(ra1 + bo + 1024);
    if (t + 1 < nt) STG(gA, 0, 0, t + 1);
    __builtin_amdgcn_s_barrier();
    asm volatile("s_waitcnt lgkmcnt(0)" ::: "memory");
    __builtin_amdgcn_sched_barrier(0);
    __builtin_amdgcn_s_setprio(1);
    #pragma unroll
    for (int mm = 0; mm < 2; ++mm)
      #pragma unroll
      for (int n = 0; n < 4; ++n) {
        acc[mm][n] = mfma16(ap[mm][0], bf[n][0], acc[mm][n]);
        acc[mm][n] = mfma16(ap[mm][1], bf[n][1], acc[mm][n]);
      }
    __builtin_amdgcn_s_setprio(0);
    __builtin_amdgcn_s_barrier();
    #pragma unroll
    for (int p = 1; p < 4; ++p) {
      const int mb = 2 * p;
      ap[0][0] = *(const bf16x8*)(ra0 + bo + mb * 1024);
      ap[0][1] = *(const bf16x8*)(ra1 + bo + mb * 1024);
      ap[1][0] = *(const bf16x8*)(ra0 + bo + (mb + 1) * 1024);
      ap[1][1] = *(const bf16x8*)(ra1 + bo + (mb + 1) * 1024);
      if (p == 1 && t + 1 < nt) STG(gA, 0, 1, t + 1);
      if (p == 2 && t + 2 < nt) STG(gB, 1, 0, t + 2);
      if (p == 3 && t + 2 < nt) STG(gB, 1, 1, t + 2);
      __builtin_amdgcn_s_barrier();
      asm volatile("s_waitcnt lgkmcnt(0)" ::: "memory");
      __builtin_amdgcn_sched_barrier(0);
      __builtin_amdgcn_s_setprio(1);
      #pragma unroll
      for (int mm = 0; mm < 2; ++mm)
        #pragma unroll
        for (int n = 0; n < 4; ++n) {
          acc[mb + mm][n] = mfma16(ap[mm][0], bf[n][0], acc[mb + mm][n]);
          acc[mb + mm][n] = mfma16(ap[mm][1], bf[n][1], acc[mb + mm][n]);
        }
      __builtin_amdgcn_s_setprio(0);
      if (p < 3) __builtin_amdgcn_s_barrier();
    }
    if (t + 1 < nt) {
      if (t + 2 < nt) {
        asm volatile("s_waitcnt vmcnt(4)" ::: "memory");
      } else {
        asm volatile("s_waitcnt vmcnt(0)" ::: "memory");
      }
      __builtin_amdgcn_s_barrier();
    }
  }

  #pragma unroll
  for (int m = 0; m < 8; ++m)
    #pragma unroll
    for (int n = 0; n < 4; ++n) {
      const int col = bn0 + wn + n * 16 + q;
      if (DOROPE) {
        const int fi = (col & 127) >> 1;
        const float sgn = (q & 1) ? 1.0f : -1.0f;
        #pragma unroll
        for (int j = 0; j < 4; ++j) {
          int row = bm0 + wm + m * 16 + g * 4 + j;
          int pos = row & (S_ - 1);
          float c = FC[pos * 64 + fi], s = FS[pos * 64 + fi];
          float own = acc[m][n][j];
          float par = __shfl_xor(own, 1);
          ((u16*)Cv)[(size_t)row * N + col] = f2bf(own * c + par * s * sgn);
        }
      } else {
        #pragma unroll
        for (int j = 0; j < 4; ++j) {
          size_t off = (size_t)(bm0 + wm + m * 16 + g * 4 + j) * N + col;
          if (OUTMODE == 1) ((float*)Cv)[off] = acc[m][n][j];
          else              ((u16*)Cv)[off]  = f2bf(acc[m][n][j]);
        }
      }
    }
}

// ------- KV projection GEMM: BM=256 x BN=128, 3-buf reg pipeline (R10) -------
// K branch (col<1024): fused RoPE (lane-pair shfl). V branch: tiled V^T layout.
__global__ __launch_bounds__(512, 2) void gemm_kv(const u16* __restrict__ A,
    const u16* __restrict__ BT, u16* __restrict__ Ck, u16* __restrict__ Cvt,
    const float* __restrict__ FC, const float* __restrict__ FS,
    int M, int N, int K) {
  extern __shared__ __attribute__((aligned(16))) u16 DL[];  // 3 x 12288 u16
  const int tid = threadIdx.x;
  const int nbx = N >> 7;                          // 16
  const int cpx = gridDim.x >> 3;
  const int swzb = (blockIdx.x & 7) * cpx + (blockIdx.x >> 3);
  const int bn0 = (swzb % nbx) << 7, bm0 = (swzb / nbx) << 8;
  const int l = tid & 63, g = l >> 4, q = l & 15;
  const int w = tid >> 6;
  const int wm = (w >> 2) * 128, wn = (w & 3) * 32;
  const int nt = K >> 5;
  f32x4 acc[8][2] = {};

  const int srow = tid >> 2, schunk = tid & 3;
  const int ssw = (schunk ^ ((srow >> 1) & 3)) << 3;
  const u16* gA0 = A  + (size_t)(bm0 + srow) * K + ssw;
  const u16* gA1 = gA0 + (size_t)128 * K;
  const u16* gB0 = BT + (size_t)(bn0 + srow) * K + ssw;

  auto STAGE = [&](int t) {
    const int kt = t << 5;
    u16* d = DL + (t % 3) * 12288;
    GLDS16(gA0 + kt, d + tid * 8);
    GLDS16(gA1 + kt, d + 4096 + tid * 8);
    GLDS16(gB0 + kt, d + 8192 + tid * 8);
  };

  const u16* ra = DL + (wm + q) * 32 + ((g ^ (((wm + q) >> 1) & 3)) << 3);
  const u16* rb = DL + 8192 + (wn + q) * 32 + ((g ^ (((wn + q) >> 1) & 3)) << 3);

  bf16x8 aC[8], aN[8], bC[2], bN[2];

  STAGE(0); STAGE(1);
  asm volatile("s_waitcnt vmcnt(3)" ::: "memory");
  __builtin_amdgcn_s_barrier();
  #pragma unroll
  for (int m = 0; m < 8; ++m) aC[m] = *(const bf16x8*)(ra + m * 512);
  #pragma unroll
  for (int n = 0; n < 2; ++n) bC[n] = *(const bf16x8*)(rb + n * 512);

  auto TILE = [&](int t, bf16x8 (&ac)[8], bf16x8 (&bc)[2],
                         bf16x8 (&an)[8], bf16x8 (&bn)[2]) {
    if (t + 2 < nt) {
      STAGE(t + 2);
      asm volatile("s_waitcnt vmcnt(3)" ::: "memory");
    } else {
      asm volatile("s_waitcnt vmcnt(0)" ::: "memory");
    }
    __builtin_amdgcn_s_barrier();
    if (t + 1 < nt) {
      const u16* pa = ra + ((t + 1) % 3) * 12288;
      const u16* pb = rb + ((t + 1) % 3) * 12288;
      #pragma unroll
      for (int m = 0; m < 8; ++m) an[m] = *(const bf16x8*)(pa + m * 512);
      #pragma unroll
      for (int n = 0; n < 2; ++n) bn[n] = *(const bf16x8*)(pb + n * 512);
    }
    __builtin_amdgcn_s_setprio(1);
    #pragma unroll
    for (int m = 0; m < 8; ++m) {
      acc[m][0] = mfma16(ac[m], bc[0], acc[m][0]);
      acc[m][1] = mfma16(ac[m], bc[1], acc[m][1]);
    }
    __builtin_amdgcn_s_setprio(0);
  };

  for (int t = 0; t < nt; t += 2) {
    TILE(t,     aC, bC, aN, bN);
    TILE(t + 1, aN, bN, aC, bC);
  }

  #pragma unroll
  for (int m = 0; m < 8; ++m)
    #pragma unroll
    for (int n = 0; n < 2; ++n) {
      int row0 = bm0 + wm + m * 16 + g * 4;
      int col  = bn0 + wn + n * 16 + q;
      if (col < 1024) {       // K head-cols: apply RoPE (uniform per 16-lane blk)
        const int fi = (col & 127) >> 1;
        const float sgn = (q & 1) ? 1.0f : -1.0f;
        #pragma unroll
        for (int j = 0; j < 4; ++j) {
          int row = row0 + j;
          int pos = row & (S_ - 1);
          float c = FC[pos * 64 + fi], s = FS[pos * 64 + fi];
          float own = acc[m][n][j];
          float par = __shfl_xor(own, 1);
          Ck[(size_t)row * 1024 + col] = f2bf(own * c + par * s * sgn);
        }
      } else {
        int c2 = col - 1024;
        u16x4 pk;
        #pragma unroll
        for (int j = 0; j < 4; ++j) pk[j] = f2bf(acc[m][n][j]);
        size_t off = ((size_t)((row0 >> 11) * KV_ + (c2 >> 7)) * 32 + ((row0 >> 6) & 31)) * 8192
                   + (size_t)(c2 & 127) * 64 + (row0 & 63);
        *(u16x4*)(Cvt + off) = pk;
      }
    }
}

// ---------------- causal GQA flash attention (swapped-QK^T, split drain) ----------------
// R11 structure + split drain: stage K,V; vmcnt(4) [K landed, V in flight];
// bar; QK^T+softmax+P (V latency hides here); vmcnt(0); bar; PV; bar.
// The old activity gate was vestigial (kt<=qt always passes) -- removed, so
// the mid-phase barrier is wave-uniform. 3 barriers/iter vs 2, but the full
// 24KB L2/HBM drain (~500-900cy) no longer serializes with compute.
// Lessons kept: launch_bounds arg2 caps VGPR at 512/N (R12); pairing at
// 4 blocks/CU (40KB LDS) is the occupancy optimum (R13).
__global__ __launch_bounds__(256, 4) void attn_kernel(
    const u16* __restrict__ Qb, const u16* __restrict__ Kb,
    const u16* __restrict__ VTg, u16* __restrict__ Ob) {
  __shared__ __attribute__((aligned(16))) u16 SM[20480]; // 40KB
  u16* Ks = SM;            // [64][128] swz(row&7)
  u16* Vs = SM + 8192;     // [128][64] swz(row&7)
  u16* Ps = SM + 16384;    // 4 waves x [16 q][64 k], 16B-chunk ^ (q&7)
  const int pr = blockIdx.x;            // 0..15
  const int h = blockIdx.y, b = blockIdx.z;
  const int kvh = h >> 2;               // N_REP = 4
  const int tid = threadIdx.x, w = tid >> 6, l = tid & 63, g = l >> 4, ql = l & 15;
  const float SL2E = 0.08838834764831845f * 1.4426950408889634f;
  const u16* Qh = Qb + (size_t)b * S_ * NQ_ + h * HD_;
  const u16* Kh = Kb + ((size_t)b * S_ * KV_ + kvh) * HD_;
  const u16* Vh = VTg + (size_t)(b * KV_ + kvh) * (32 * 8192);
  u16* Oh = Ob + (size_t)b * S_ * NQ_ + h * HD_;

  for (int ph = 0; ph < 2; ++ph) {
    const int qt = ph ? pr : 31 - pr;
    __syncthreads();   // SM (epilogue scratch) free before restaging
    bf16x8 aq[4];
    #pragma unroll
    for (int kk = 0; kk < 4; ++kk)
      aq[kk] = *(const bf16x8*)(Qh + (size_t)(qt * 64 + w * 16 + ql) * NQ_ + kk * 32 + g * 8);

    f32x4 o[8] = {};
    float mrow = -3.0e38f, lrow = 0.f;

    const int nkt = qt + 1;
    for (int kt = 0; kt < nkt; ++kt) {
      #pragma unroll
      for (int p = 0; p < 4; ++p) {   // K: [64][128]  (issued first -> oldest)
        int c = tid + p * 256;
        int row = c >> 4, slot = c & 15;
        GLDS16(Kh + (size_t)(kt * 64 + row) * (KV_ * HD_) + ((slot ^ (row & 7)) << 3), Ks + c * 8);
      }
      #pragma unroll
      for (int p = 0; p < 4; ++p) {   // V^T: [128][64] from contiguous 16KB tile
        int c = tid + p * 256;
        int row = c >> 3, slot = c & 7;
        GLDS16(Vh + (size_t)kt * 8192 + row * 64 + ((slot ^ (row & 7)) << 3), Vs + c * 8);
      }
      asm volatile("s_waitcnt vmcnt(4)" ::: "memory");   // K landed; V in flight
      __builtin_amdgcn_s_barrier();                      // K published

      // ---- S^T = K * Q^T ----
      f32x4 sc[4] = {};
      #pragma unroll
      for (int kk = 0; kk < 4; ++kk) {
        bf16x8 bk[4];
        #pragma unroll
        for (int n = 0; n < 4; ++n) {
          int row = n * 16 + ql;
          bk[n] = *(const bf16x8*)(Ks + row * 128 + (((kk * 4 + g) ^ (row & 7)) << 3));
        }
        #pragma unroll
        for (int n = 0; n < 4; ++n)
          sc[n] = mfma16(bk[n], aq[kk], sc[n]);
      }
      // ---- causal mask (diagonal tiles only); lane holds k=kt*64+n*16+g*4+j, q=ql ----
      const int qglob = qt * 64 + w * 16 + ql;
      if (kt * 64 + 63 > qt * 64 + w * 16) {
        #pragma unroll
        for (int n = 0; n < 4; ++n)
          #pragma unroll
          for (int j = 0; j < 4; ++j)
            if (kt * 64 + n * 16 + g * 4 + j > qglob) sc[n][j] = -3.0e38f;
      }
      // ---- online softmax: in-lane over 16 k-vals, then xor16/xor32 ----
      float mx = sc[0][0];
      #pragma unroll
      for (int n = 0; n < 4; ++n)
        #pragma unroll
        for (int j = 0; j < 4; ++j) mx = fmaxf(mx, sc[n][j]);
      mx = fmaxf(mx, __shfl_xor(mx, 16));
      mx = fmaxf(mx, __shfl_xor(mx, 32));
      if (!__all(mx - mrow <= 16.0f)) {      // defer-max: P bounded by 2^2.04
        float mnew = fmaxf(mrow, mx);
        float f = exp2f((mrow - mnew) * SL2E);
        lrow *= f;
        #pragma unroll
        for (int m = 0; m < 8; ++m) o[m] *= f;
        mrow = mnew;
      }
      float rs = 0.f;
      #pragma unroll
      for (int n = 0; n < 4; ++n)
        #pragma unroll
        for (int j = 0; j < 4; ++j) {
          float pv = exp2f((sc[n][j] - mrow) * SL2E);
          sc[n][j] = pv; rs += pv;
        }
      rs += __shfl_xor(rs, 16);
      rs += __shfl_xor(rs, 32);
      lrow += rs;
      // ---- P -> LDS: [16 q][64 k], 16B chunk ^ (q&7); 4 x u16x4 writes ----
      u16* Pw = Ps + w * 1024;
      #pragma unroll
      for (int n = 0; n < 4; ++n) {
        u16x4 pk;
        #pragma unroll
        for (int j = 0; j < 4; ++j) pk[j] = f2bft(sc[n][j]);
        *(u16x4*)(Pw + ql * 64 + (((n * 2 + (g >> 1)) ^ (ql & 7)) << 3) + (g & 1) * 4) = pk;
      }
      asm volatile("s_waitcnt vmcnt(0)" ::: "memory");   // V landed
      __builtin_amdgcn_s_barrier();                      // V published
      // ---- PV: O^T = V^T * P^T ----
      #pragma unroll
      for (int kk2 = 0; kk2 < 2; ++kk2) {
        bf16x8 bp = *(const bf16x8*)(Pw + ql * 64 + (((kk2 * 4 + g) ^ (ql & 7)) << 3));
        #pragma unroll
        for (int m = 0; m < 8; ++m) {
          int row = m * 16 + ql;
          bf16x8 av = *(const bf16x8*)(Vs + row * 64 + (((kk2 * 4 + g) ^ (row & 7)) << 3));
          o[m] = mfma16(av, bp, o[m]);
        }
      }
      __builtin_amdgcn_s_barrier();   // all waves done with Ks/Vs before restage
    }
    // ---- epilogue: normalize (lane-local), transpose via LDS, store ----
    __syncthreads();
    u16* OS = SM; // [64][136]
    float linv = 1.0f / lrow;
    #pragma unroll
    for (int m = 0; m < 8; ++m)
      #pragma unroll
      for (int j = 0; j < 4; ++j)
        OS[(w * 16 + ql) * 136 + m * 16 + g * 4 + j] = f2bf(o[m][j] * linv);
    __syncthreads();
    #pragma unroll
    for (int p = 0; p < 4; ++p) {
      int c = tid + p * 256;
      int row = c >> 4, col8 = c & 15;
      u16x8 d = *(const u16x8*)(OS + row * 136 + col8 * 8);
      *(u16x8*)(Oh + (size_t)(qt * 64 + row) * NQ_ + col8 * 8) = d;
    }
  }
}

extern "C" void kernel_launch(void* const* d_in, const int* in_sizes, int n_in,
                              void* d_out, int out_size, void* d_ws, size_t ws_size,
                              hipStream_t stream) {
  const float* x  = (const float*)d_in[0];
  const float* fc = (const float*)d_in[1];
  const float* fs = (const float*)d_in[2];
  // d_in[3] = mask (causal, applied analytically)
  const float* wq = (const float*)d_in[4];
  const float* wk = (const float*)d_in[5];
  const float* wv = (const float*)d_in[6];
  const float* wo = (const float*)d_in[7];

  char* ws = (char*)d_ws;
  u16* xb  = (u16*)(ws + 0);          // 33554432 B
  u16* wqT = (u16*)(ws + 33554432);   // 33554432
  u16* wkT = (u16*)(ws + 67108864);   // 8388608   (wkT||wvT = [2048][4096])
  u16* wvT = (u16*)(ws + 75497472);   // 8388608
  u16* woT = (u16*)(ws + 83886080);   // 33554432
  u16* qb  = (u16*)(ws + 117440512);  // 33554432
  u16* kb  = (u16*)(ws + 150994944);  // 8388608
  u16* vtg = (u16*)(ws + 159383552);  // 8388608  (V^T tiled: [B][KV][32][128][64])
  u16* ob  = (u16*)(ws + 167772160);  // 33554432  -> total 201326592
  if (ws_size < 201326592u) return;

  cvt_bf16<<<(M_ * D_) / (8 * 256), 256, 0, stream>>>(x, xb, M_ * D_);
  tcvt<<<dim3(NQ_ / 64, D_ / 64), 256, 0, stream>>>(wq, wqT, D_, NQ_);
  tcvt<<<dim3(NKV_ / 64, D_ / 64), 256, 0, stream>>>(wk, wkT, D_, NKV_);
  tcvt<<<dim3(NKV_ / 64, D_ / 64), 256, 0, stream>>>(wv, wvT, D_, NKV_);
  tcvt<<<dim3(D_ / 64, NQ_ / 64), 256, 0, stream>>>(wo, woT, NQ_, D_);

  // Q projection + fused RoPE (8-phase schedule, 128KB dynamic LDS)
  gemm256<0, true><<<(NQ_ / 256) * (M_ / 256), 512, 131072, stream>>>(
      xb, wqT, qb, fc, fs, M_, NQ_, D_);
  // fused K+V projection (K branch: fused RoPE; V: tiled V^T layout)
  gemm_kv<<<(2048 / 128) * (M_ / 256), 512, 73728, stream>>>(
      xb, wkT, kb, vtg, fc, fs, M_, 2048, D_);

  attn_kernel<<<dim3(16, H_, B_), 256, 0, stream>>>(qb, kb, vtg, ob);

  gemm256<1, false><<<(D_ / 256) * (M_ / 256), 512, 131072, stream>>>(
      ob, woT, d_out, fc, fs, M_, D_, NQ_);
}

// Round 21
// 503.610 us; speedup vs baseline: 7.7682x; 1.0081x over previous
//
#include <hip/hip_runtime.h>
#include <stdint.h>

#define B_ 2
#define S_ 2048
#define D_ 4096
#define H_ 32
#define KV_ 8
#define HD_ 128
#define M_ (B_*S_)          // 4096 rows (b*S+s)
#define NQ_ (H_*HD_)        // 4096
#define NKV_ (KV_*HD_)      // 1024

typedef unsigned short u16;
typedef __bf16 bf16x8 __attribute__((ext_vector_type(8)));
typedef float f32x4 __attribute__((ext_vector_type(4)));
typedef u16 u16x8 __attribute__((ext_vector_type(8)));
typedef u16 u16x4 __attribute__((ext_vector_type(4)));

__device__ __forceinline__ u16 f2bf(float f) {
  union { float f; unsigned u; } v; v.f = f;
  unsigned r = v.u + 0x7fffu + ((v.u >> 16) & 1u);
  return (u16)(r >> 16);
}
__device__ __forceinline__ u16 f2bft(float f) {  // truncating (for P; values in [0,4.2])
  union { float f; unsigned u; } v; v.f = f;
  return (u16)(v.u >> 16);
}
__device__ __forceinline__ float bf2f(u16 u) {
  union { unsigned u; float f; } v; v.u = ((unsigned)u) << 16;
  return v.f;
}
__device__ __forceinline__ f32x4 mfma16(bf16x8 a, bf16x8 b, f32x4 c) {
  return __builtin_amdgcn_mfma_f32_16x16x32_bf16(a, b, c, 0, 0, 0);
}

#define GLDS16(gp, lp) __builtin_amdgcn_global_load_lds( \
    (const __attribute__((address_space(1))) unsigned int*)(gp), \
    (__attribute__((address_space(3))) unsigned int*)(lp), 16, 0, 0)

// -------- fused prologue: x fp32->bf16 + 4 weight transpose+converts --------
// 1-D grid, region-decoded: id<8192 -> cvt (2048 elems/block); else transpose
// blocks t = id-8192 over (ry, rx) = (t/160, t%160); rx regions map to
// wq/wk/wv/wo. Per-block-uniform branches. Replaces 5 dispatches with 1.
__global__ __launch_bounds__(256) void prep_kernel(
    const float* __restrict__ x,  const float* __restrict__ wq,
    const float* __restrict__ wk, const float* __restrict__ wv,
    const float* __restrict__ wo,
    u16* __restrict__ xb,  u16* __restrict__ wqT, u16* __restrict__ wkT,
    u16* __restrict__ wvT, u16* __restrict__ woT) {
  __shared__ float tf[64][65];
  const int id = blockIdx.x;
  if (id < 8192) {                      // ---- cvt: x -> xb (bf16) ----
    int i = id * 2048 + threadIdx.x * 8;
    float4 a = *(const float4*)(x + i);
    float4 b = *(const float4*)(x + i + 4);
    u16x8 o;
    o[0]=f2bf(a.x); o[1]=f2bf(a.y); o[2]=f2bf(a.z); o[3]=f2bf(a.w);
    o[4]=f2bf(b.x); o[5]=f2bf(b.y); o[6]=f2bf(b.z); o[7]=f2bf(b.w);
    *(u16x8*)(xb + i) = o;
    return;
  }
  // ---- transpose+convert: out[c][r] = in[r][c], 64x64 tile ----
  const int t = id - 8192;
  const int ry = t / 160, rx = t % 160;
  const float* in; u16* out; int C, cx, R;
  if (rx < 64)      { in = wq; out = wqT; C = NQ_;  cx = rx;      R = D_;  }
  else if (rx < 80) { in = wk; out = wkT; C = NKV_; cx = rx - 64; R = D_;  }
  else if (rx < 96) { in = wv; out = wvT; C = NKV_; cx = rx - 80; R = D_;  }
  else              { in = wo; out = woT; C = D_;   cx = rx - 96; R = NQ_; }
  const int c0 = cx * 64, r0 = ry * 64;
  const int l16 = threadIdx.x & 15, r16 = threadIdx.x >> 4;
  #pragma unroll
  for (int p = 0; p < 4; ++p) {
    int r = p * 16 + r16;
    float4 v = *(const float4*)(in + (size_t)(r0 + r) * C + c0 + l16 * 4);
    tf[r][l16 * 4 + 0] = v.x; tf[r][l16 * 4 + 1] = v.y;
    tf[r][l16 * 4 + 2] = v.z; tf[r][l16 * 4 + 3] = v.w;
  }
  __syncthreads();
  const int oc = threadIdx.x >> 2, ch = threadIdx.x & 3;
  u16x8 o1, o2;
  #pragma unroll
  for (int i = 0; i < 8; ++i) o1[i] = f2bf(tf[ch * 16 + i][oc]);
  #pragma unroll
  for (int i = 0; i < 8; ++i) o2[i] = f2bf(tf[ch * 16 + 8 + i][oc]);
  *(u16x8*)(out + (size_t)(c0 + oc) * R + r0 + ch * 16) = o1;
  *(u16x8*)(out + (size_t)(c0 + oc) * R + r0 + ch * 16 + 8) = o2;
}

// ------- 256x256 GEMM, m201-style 8-phase (4 phases/K-step), BK=64, 2 dbufs -------
// (R18; 40-42% MfmaUtil plateau robust across coarse/4-phase/8-phase/3-buf.)
template<int OUTMODE, bool DOROPE>
__global__ __launch_bounds__(512, 2) void gemm256(const u16* __restrict__ A,
    const u16* __restrict__ BT, void* __restrict__ Cv,
    const float* __restrict__ FC, const float* __restrict__ FS,
    int M, int N, int K) {
  extern __shared__ __attribute__((aligned(16))) u16 DL[];  // 2 x (A 16384 + B 16384) u16 = 128KB
  const int tid = threadIdx.x;
  const int nbx = N >> 8;
  const int cpx = gridDim.x >> 3;                 // grid % 8 == 0
  const int swzb = (blockIdx.x & 7) * cpx + (blockIdx.x >> 3);
  const int bn0 = (swzb % nbx) << 8, bm0 = (swzb / nbx) << 8;
  const int l = tid & 63, g = l >> 4, q = l & 15;
  const int w = tid >> 6;
  const int wm = (w >> 2) * 128, wn = (w & 3) * 64;
  const int nt = K >> 6;   // BK = 64
  f32x4 acc[8][4] = {};

  const int srow = tid >> 3, slot = tid & 7;
  const int ssw = (slot ^ (srow & 7)) << 3;
  const u16* gA = A  + (size_t)(bm0 + srow) * K + ssw;
  const u16* gB = BT + (size_t)(bn0 + srow) * K + ssw;

  auto STG = [&](const u16* gbase, int oB, int h, int t) {
    const int kt = t << 6;
    u16* d = DL + (t & 1) * 32768 + oB * 16384 + h * 8192 + tid * 8;
    GLDS16(gbase + (size_t)(h * 128) * K + kt, d);
    GLDS16(gbase + (size_t)(h * 128 + 64) * K + kt, d + 4096);
  };

  const u16* ra0 = DL + (wm + q) * 64 + ((g ^ (q & 7)) << 3);
  const u16* ra1 = DL + (wm + q) * 64 + (((4 + g) ^ (q & 7)) << 3);
  const u16* rb0 = DL + 16384 + (wn + q) * 64 + ((g ^ (q & 7)) << 3);
  const u16* rb1 = DL + 16384 + (wn + q) * 64 + (((4 + g) ^ (q & 7)) << 3);

  STG(gA, 0, 0, 0); STG(gA, 0, 1, 0);
  STG(gB, 1, 0, 0); STG(gB, 1, 1, 0);
  STG(gB, 1, 0, 1); STG(gB, 1, 1, 1);
  asm volatile("s_waitcnt vmcnt(4)" ::: "memory");
  __builtin_amdgcn_s_barrier();

  for (int t = 0; t < nt; ++t) {
    const int bo = (t & 1) * 32768;
    bf16x8 bf[4][2], ap[2][2];
    #pragma unroll
    for (int n = 0; n < 4; ++n) {
      bf[n][0] = *(const bf16x8*)(rb0 + bo + n * 1024);
      bf[n][1] = *(const bf16x8*)(rb1 + bo + n * 1024);
    }
    ap[0][0] = *(const bf16x8*)(ra0 + bo);
    ap[0][1] = *(const bf16x8*)(ra1 + bo);
    ap[1][0] = *(const bf16x8*)(ra0 + bo + 1024);
    ap[1][1] = *(const bf16x8*)(ra1 + bo + 1024);
    if (t + 1 < nt) STG(gA, 0, 0, t + 1);
    __builtin_amdgcn_s_barrier();
    asm volatile("s_waitcnt lgkmcnt(0)" ::: "memory");
    __builtin_amdgcn_sched_barrier(0);
    __builtin_amdgcn_s_setprio(1);
    #pragma unroll
    for (int mm = 0; mm < 2; ++mm)
      #pragma unroll
      for (int n = 0; n < 4; ++n) {
        acc[mm][n] = mfma16(ap[mm][0], bf[n][0], acc[mm][n]);
        acc[mm][n] = mfma16(ap[mm][1], bf[n][1], acc[mm][n]);
      }
    __builtin_amdgcn_s_setprio(0);
    __builtin_amdgcn_s_barrier();
    #pragma unroll
    for (int p = 1; p < 4; ++p) {
      const int mb = 2 * p;
      ap[0][0] = *(const bf16x8*)(ra0 + bo + mb * 1024);
      ap[0][1] = *(const bf16x8*)(ra1 + bo + mb * 1024);
      ap[1][0] = *(const bf16x8*)(ra0 + bo + (mb + 1) * 1024);
      ap[1][1] = *(const bf16x8*)(ra1 + bo + (mb + 1) * 1024);
      if (p == 1 && t + 1 < nt) STG(gA, 0, 1, t + 1);
      if (p == 2 && t + 2 < nt) STG(gB, 1, 0, t + 2);
      if (p == 3 && t + 2 < nt) STG(gB, 1, 1, t + 2);
      __builtin_amdgcn_s_barrier();
      asm volatile("s_waitcnt lgkmcnt(0)" ::: "memory");
      __builtin_amdgcn_sched_barrier(0);
      __builtin_amdgcn_s_setprio(1);
      #pragma unroll
      for (int mm = 0; mm < 2; ++mm)
        #pragma unroll
        for (int n = 0; n < 4; ++n) {
          acc[mb + mm][n] = mfma16(ap[mm][0], bf[n][0], acc[mb + mm][n]);
          acc[mb + mm][n] = mfma16(ap[mm][1], bf[n][1], acc[mb + mm][n]);
        }
      __builtin_amdgcn_s_setprio(0);
      if (p < 3) __builtin_amdgcn_s_barrier();
    }
    if (t + 1 < nt) {
      if (t + 2 < nt) {
        asm volatile("s_waitcnt vmcnt(4)" ::: "memory");
      } else {
        asm volatile("s_waitcnt vmcnt(0)" ::: "memory");
      }
      __builtin_amdgcn_s_barrier();
    }
  }

  #pragma unroll
  for (int m = 0; m < 8; ++m)
    #pragma unroll
    for (int n = 0; n < 4; ++n) {
      const int col = bn0 + wn + n * 16 + q;
      if (DOROPE) {
        const int fi = (col & 127) >> 1;
        const float sgn = (q & 1) ? 1.0f : -1.0f;
        #pragma unroll
        for (int j = 0; j < 4; ++j) {
          int row = bm0 + wm + m * 16 + g * 4 + j;
          int pos = row & (S_ - 1);
          float c = FC[pos * 64 + fi], s = FS[pos * 64 + fi];
          float own = acc[m][n][j];
          float par = __shfl_xor(own, 1);
          ((u16*)Cv)[(size_t)row * N + col] = f2bf(own * c + par * s * sgn);
        }
      } else {
        #pragma unroll
        for (int j = 0; j < 4; ++j) {
          size_t off = (size_t)(bm0 + wm + m * 16 + g * 4 + j) * N + col;
          if (OUTMODE == 1) ((float*)Cv)[off] = acc[m][n][j];
          else              ((u16*)Cv)[off]  = f2bf(acc[m][n][j]);
        }
      }
    }
}

// ------- KV projection GEMM: BM=256 x BN=128, 3-buf reg pipeline (R10) -------
// K branch (col<1024): fused RoPE (lane-pair shfl). V branch: tiled V^T layout.
__global__ __launch_bounds__(512, 2) void gemm_kv(const u16* __restrict__ A,
    const u16* __restrict__ BT, u16* __restrict__ Ck, u16* __restrict__ Cvt,
    const float* __restrict__ FC, const float* __restrict__ FS,
    int M, int N, int K) {
  extern __shared__ __attribute__((aligned(16))) u16 DL[];  // 3 x 12288 u16
  const int tid = threadIdx.x;
  const int nbx = N >> 7;                          // 16
  const int cpx = gridDim.x >> 3;
  const int swzb = (blockIdx.x & 7) * cpx + (blockIdx.x >> 3);
  const int bn0 = (swzb % nbx) << 7, bm0 = (swzb / nbx) << 8;
  const int l = tid & 63, g = l >> 4, q = l & 15;
  const int w = tid >> 6;
  const int wm = (w >> 2) * 128, wn = (w & 3) * 32;
  const int nt = K >> 5;
  f32x4 acc[8][2] = {};

  const int srow = tid >> 2, schunk = tid & 3;
  const int ssw = (schunk ^ ((srow >> 1) & 3)) << 3;
  const u16* gA0 = A  + (size_t)(bm0 + srow) * K + ssw;
  const u16* gA1 = gA0 + (size_t)128 * K;
  const u16* gB0 = BT + (size_t)(bn0 + srow) * K + ssw;

  auto STAGE = [&](int t) {
    const int kt = t << 5;
    u16* d = DL + (t % 3) * 12288;
    GLDS16(gA0 + kt, d + tid * 8);
    GLDS16(gA1 + kt, d + 4096 + tid * 8);
    GLDS16(gB0 + kt, d + 8192 + tid * 8);
  };

  const u16* ra = DL + (wm + q) * 32 + ((g ^ (((wm + q) >> 1) & 3)) << 3);
  const u16* rb = DL + 8192 + (wn + q) * 32 + ((g ^ (((wn + q) >> 1) & 3)) << 3);

  bf16x8 aC[8], aN[8], bC[2], bN[2];

  STAGE(0); STAGE(1);
  asm volatile("s_waitcnt vmcnt(3)" ::: "memory");
  __builtin_amdgcn_s_barrier();
  #pragma unroll
  for (int m = 0; m < 8; ++m) aC[m] = *(const bf16x8*)(ra + m * 512);
  #pragma unroll
  for (int n = 0; n < 2; ++n) bC[n] = *(const bf16x8*)(rb + n * 512);

  auto TILE = [&](int t, bf16x8 (&ac)[8], bf16x8 (&bc)[2],
                         bf16x8 (&an)[8], bf16x8 (&bn)[2]) {
    if (t + 2 < nt) {
      STAGE(t + 2);
      asm volatile("s_waitcnt vmcnt(3)" ::: "memory");
    } else {
      asm volatile("s_waitcnt vmcnt(0)" ::: "memory");
    }
    __builtin_amdgcn_s_barrier();
    if (t + 1 < nt) {
      const u16* pa = ra + ((t + 1) % 3) * 12288;
      const u16* pb = rb + ((t + 1) % 3) * 12288;
      #pragma unroll
      for (int m = 0; m < 8; ++m) an[m] = *(const bf16x8*)(pa + m * 512);
      #pragma unroll
      for (int n = 0; n < 2; ++n) bn[n] = *(const bf16x8*)(pb + n * 512);
    }
    __builtin_amdgcn_s_setprio(1);
    #pragma unroll
    for (int m = 0; m < 8; ++m) {
      acc[m][0] = mfma16(ac[m], bc[0], acc[m][0]);
      acc[m][1] = mfma16(ac[m], bc[1], acc[m][1]);
    }
    __builtin_amdgcn_s_setprio(0);
  };

  for (int t = 0; t < nt; t += 2) {
    TILE(t,     aC, bC, aN, bN);
    TILE(t + 1, aN, bN, aC, bC);
  }

  #pragma unroll
  for (int m = 0; m < 8; ++m)
    #pragma unroll
    for (int n = 0; n < 2; ++n) {
      int row0 = bm0 + wm + m * 16 + g * 4;
      int col  = bn0 + wn + n * 16 + q;
      if (col < 1024) {       // K head-cols: apply RoPE (uniform per 16-lane blk)
        const int fi = (col & 127) >> 1;
        const float sgn = (q & 1) ? 1.0f : -1.0f;
        #pragma unroll
        for (int j = 0; j < 4; ++j) {
          int row = row0 + j;
          int pos = row & (S_ - 1);
          float c = FC[pos * 64 + fi], s = FS[pos * 64 + fi];
          float own = acc[m][n][j];
          float par = __shfl_xor(own, 1);
          Ck[(size_t)row * 1024 + col] = f2bf(own * c + par * s * sgn);
        }
      } else {
        int c2 = col - 1024;
        u16x4 pk;
        #pragma unroll
        for (int j = 0; j < 4; ++j) pk[j] = f2bf(acc[m][n][j]);
        size_t off = ((size_t)((row0 >> 11) * KV_ + (c2 >> 7)) * 32 + ((row0 >> 6) & 31)) * 8192
                   + (size_t)(c2 & 127) * 64 + (row0 & 63);
        *(u16x4*)(Cvt + off) = pk;
      }
    }
}

// ---------------- causal GQA flash attention (swapped-QK^T) ----------------
// R18-exact version (138us, absmax 0.03125 across R14-R18). R19/R20 LESSON:
// split-drain vmcnt(4) across TWO staging groups assumed source-order issue
// of the K and V gload groups -- the compiler may interleave them, making
// vmcnt(4) retire a K/V mix and leaving K-writes in flight at the K-publish
// barrier (stale-K race; absmax 0.031->0.067->0.235 escalation). Counted
// vmcnt across multiple staging groups is only safe when gated at vmcnt(0).
// Other lessons: launch_bounds arg2 caps VGPR at 512/N (R12); pairing at
// 4 blocks/CU (40KB LDS) is the occupancy optimum (R13).
__global__ __launch_bounds__(256, 4) void attn_kernel(
    const u16* __restrict__ Qb, const u16* __restrict__ Kb,
    const u16* __restrict__ VTg, u16* __restrict__ Ob) {
  __shared__ __attribute__((aligned(16))) u16 SM[20480]; // 40KB
  u16* Ks = SM;            // [64][128] swz(row&7)
  u16* Vs = SM + 8192;     // [128][64] swz(row&7)
  u16* Ps = SM + 16384;    // 4 waves x [16 q][64 k], 16B-chunk ^ (q&7)
  const int pr = blockIdx.x;            // 0..15
  const int h = blockIdx.y, b = blockIdx.z;
  const int kvh = h >> 2;               // N_REP = 4
  const int tid = threadIdx.x, w = tid >> 6, l = tid & 63, g = l >> 4, ql = l & 15;
  const float SL2E = 0.08838834764831845f * 1.4426950408889634f;
  const u16* Qh = Qb + (size_t)b * S_ * NQ_ + h * HD_;
  const u16* Kh = Kb + ((size_t)b * S_ * KV_ + kvh) * HD_;
  const u16* Vh = VTg + (size_t)(b * KV_ + kvh) * (32 * 8192);
  u16* Oh = Ob + (size_t)b * S_ * NQ_ + h * HD_;

  for (int ph = 0; ph < 2; ++ph) {
    const int qt = ph ? pr : 31 - pr;
    __syncthreads();   // SM (epilogue scratch) free before restaging
    bf16x8 aq[4];
    #pragma unroll
    for (int kk = 0; kk < 4; ++kk)
      aq[kk] = *(const bf16x8*)(Qh + (size_t)(qt * 64 + w * 16 + ql) * NQ_ + kk * 32 + g * 8);

    f32x4 o[8] = {};
    float mrow = -3.0e38f, lrow = 0.f;

    const int nkt = qt + 1;
    for (int kt = 0; kt < nkt; ++kt) {
      #pragma unroll
      for (int p = 0; p < 4; ++p) {   // K: [64][128]
        int c = tid + p * 256;
        int row = c >> 4, slot = c & 15;
        GLDS16(Kh + (size_t)(kt * 64 + row) * (KV_ * HD_) + ((slot ^ (row & 7)) << 3), Ks + c * 8);
      }
      #pragma unroll
      for (int p = 0; p < 4; ++p) {   // V^T: [128][64] from contiguous 16KB tile
        int c = tid + p * 256;
        int row = c >> 3, slot = c & 7;
        GLDS16(Vh + (size_t)kt * 8192 + row * 64 + ((slot ^ (row & 7)) << 3), Vs + c * 8);
      }
      asm volatile("s_waitcnt vmcnt(0)" ::: "memory");
      __builtin_amdgcn_s_barrier();

      if (kt * 64 <= qt * 64 + w * 16 + 15) {   // wave-uniform activity gate
        // ---- S^T = K * Q^T ----
        f32x4 sc[4] = {};
        #pragma unroll
        for (int kk = 0; kk < 4; ++kk) {
          bf16x8 bk[4];
          #pragma unroll
          for (int n = 0; n < 4; ++n) {
            int row = n * 16 + ql;
            bk[n] = *(const bf16x8*)(Ks + row * 128 + (((kk * 4 + g) ^ (row & 7)) << 3));
          }
          #pragma unroll
          for (int n = 0; n < 4; ++n)
            sc[n] = mfma16(bk[n], aq[kk], sc[n]);
        }
        // ---- causal mask (diagonal tiles only); lane holds k=kt*64+n*16+g*4+j, q=ql ----
        const int qglob = qt * 64 + w * 16 + ql;
        if (kt * 64 + 63 > qt * 64 + w * 16) {
          #pragma unroll
          for (int n = 0; n < 4; ++n)
            #pragma unroll
            for (int j = 0; j < 4; ++j)
              if (kt * 64 + n * 16 + g * 4 + j > qglob) sc[n][j] = -3.0e38f;
        }
        // ---- online softmax: in-lane over 16 k-vals, then xor16/xor32 ----
        float mx = sc[0][0];
        #pragma unroll
        for (int n = 0; n < 4; ++n)
          #pragma unroll
          for (int j = 0; j < 4; ++j) mx = fmaxf(mx, sc[n][j]);
        mx = fmaxf(mx, __shfl_xor(mx, 16));
        mx = fmaxf(mx, __shfl_xor(mx, 32));
        if (!__all(mx - mrow <= 16.0f)) {      // defer-max: P bounded by 2^2.04
          float mnew = fmaxf(mrow, mx);
          float f = exp2f((mrow - mnew) * SL2E);
          lrow *= f;
          #pragma unroll
          for (int m = 0; m < 8; ++m) o[m] *= f;
          mrow = mnew;
        }
        float rs = 0.f;
        #pragma unroll
        for (int n = 0; n < 4; ++n)
          #pragma unroll
          for (int j = 0; j < 4; ++j) {
            float pv = exp2f((sc[n][j] - mrow) * SL2E);
            sc[n][j] = pv; rs += pv;
          }
        rs += __shfl_xor(rs, 16);
        rs += __shfl_xor(rs, 32);
        lrow += rs;
        // ---- P -> LDS: [16 q][64 k], 16B chunk ^ (q&7); 4 x u16x4 writes ----
        u16* Pw = Ps + w * 1024;
        #pragma unroll
        for (int n = 0; n < 4; ++n) {
          u16x4 pk;
          #pragma unroll
          for (int j = 0; j < 4; ++j) pk[j] = f2bft(sc[n][j]);
          *(u16x4*)(Pw + ql * 64 + (((n * 2 + (g >> 1)) ^ (ql & 7)) << 3) + (g & 1) * 4) = pk;
        }
        // ---- PV: O^T = V^T * P^T ----
        #pragma unroll
        for (int kk2 = 0; kk2 < 2; ++kk2) {
          bf16x8 bp = *(const bf16x8*)(Pw + ql * 64 + (((kk2 * 4 + g) ^ (ql & 7)) << 3));
          #pragma unroll
          for (int m = 0; m < 8; ++m) {
            int row = m * 16 + ql;
            bf16x8 av = *(const bf16x8*)(Vs + row * 64 + (((kk2 * 4 + g) ^ (row & 7)) << 3));
            o[m] = mfma16(av, bp, o[m]);
          }
        }
      }
      __builtin_amdgcn_s_barrier();   // all waves done with Ks/Vs before restage
    }
    // ---- epilogue: normalize (lane-local), transpose via LDS, store ----
    __syncthreads();
    u16* OS = SM; // [64][136]
    float linv = 1.0f / lrow;
    #pragma unroll
    for (int m = 0; m < 8; ++m)
      #pragma unroll
      for (int j = 0; j < 4; ++j)
        OS[(w * 16 + ql) * 136 + m * 16 + g * 4 + j] = f2bf(o[m][j] * linv);
    __syncthreads();
    #pragma unroll
    for (int p = 0; p < 4; ++p) {
      int c = tid + p * 256;
      int row = c >> 4, col8 = c & 15;
      u16x8 d = *(const u16x8*)(OS + row * 136 + col8 * 8);
      *(u16x8*)(Oh + (size_t)(qt * 64 + row) * NQ_ + col8 * 8) = d;
    }
  }
}

extern "C" void kernel_launch(void* const* d_in, const int* in_sizes, int n_in,
                              void* d_out, int out_size, void* d_ws, size_t ws_size,
                              hipStream_t stream) {
  const float* x  = (const float*)d_in[0];
  const float* fc = (const float*)d_in[1];
  const float* fs = (const float*)d_in[2];
  // d_in[3] = mask (causal, applied analytically)
  const float* wq = (const float*)d_in[4];
  const float* wk = (const float*)d_in[5];
  const float* wv = (const float*)d_in[6];
  const float* wo = (const float*)d_in[7];

  char* ws = (char*)d_ws;
  u16* xb  = (u16*)(ws + 0);          // 33554432 B
  u16* wqT = (u16*)(ws + 33554432);   // 33554432
  u16* wkT = (u16*)(ws + 67108864);   // 8388608   (wkT||wvT = [2048][4096])
  u16* wvT = (u16*)(ws + 75497472);   // 8388608
  u16* woT = (u16*)(ws + 83886080);   // 33554432
  u16* qb  = (u16*)(ws + 117440512);  // 33554432
  u16* kb  = (u16*)(ws + 150994944);  // 8388608
  u16* vtg = (u16*)(ws + 159383552);  // 8388608  (V^T tiled: [B][KV][32][128][64])
  u16* ob  = (u16*)(ws + 167772160);  // 33554432  -> total 201326592
  if (ws_size < 201326592u) return;

  // fused prologue: cvt(x) + 4 transposes in one dispatch
  prep_kernel<<<8192 + 160 * 64, 256, 0, stream>>>(
      x, wq, wk, wv, wo, xb, wqT, wkT, wvT, woT);

  // Q projection + fused RoPE (8-phase schedule, 128KB dynamic LDS)
  gemm256<0, true><<<(NQ_ / 256) * (M_ / 256), 512, 131072, stream>>>(
      xb, wqT, qb, fc, fs, M_, NQ_, D_);
  // fused K+V projection (K branch: fused RoPE; V: tiled V^T layout)
  gemm_kv<<<(2048 / 128) * (M_ / 256), 512, 73728, stream>>>(
      xb, wkT, kb, vtg, fc, fs, M_, 2048, D_);

  attn_kernel<<<dim3(16, H_, B_), 256, 0, stream>>>(qb, kb, vtg, ob);

  gemm256<1, false><<<(D_ / 256) * (M_ / 256), 512, 131072, stream>>>(
      ob, woT, d_out, fc, fs, M_, D_, NQ_);
}